// Round 1
// baseline (568.980 us; speedup 1.0000x reference)
//
#include <hip/hip_runtime.h>
#include <math.h>

// Problem constants: B=8, C=64 (in), OC=64 (out), H=W=128, K=3x3=9, PAD=1.
#define Bn 8
#define Cin 64
#define Cout 64
#define Hn 128
#define Wn 128
#define HW 16384          // H*W
#define NPIX 131072       // B*H*W
#define EPSv 1e-5f

// ws layout (floats)
#define OFF_OFF  0                       // 8*18*16384 = 2359296
#define MASK_OFF 2359296                 // 8*9*16384  = 1179648
#define WA_OFF   3538944                 // 64*9*28    = 16128  (conv weights, [cin][t][oc'] oc' padded to 28)
#define WB_OFF   3555072                 // 9*64*64    = 36864  (deform weights, [k][c][oc])
#define STAT_OFF 3591936                 // 128 (mean[64], var[64])

// ---------------- prep: reorder weights ----------------
__global__ __launch_bounds__(256) void prep_kernel(
    const float* __restrict__ off_w, const float* __restrict__ mod_w,
    const float* __restrict__ w, float* __restrict__ wA, float* __restrict__ wB) {
  int i = blockIdx.x * 256 + threadIdx.x;
  if (i < 16128) {
    // wA[(cin*9 + t)*28 + oc'], oc'<18 -> off_w[oc'][cin][t], 18..26 -> mod_w[oc'-18][cin][t], 27 -> 0
    int oc = i % 28;
    int rt = i / 28;
    int t = rt % 9;
    int cin = rt / 9;
    float v = 0.f;
    if (oc < 18) v = off_w[(oc * 64 + cin) * 9 + t];
    else if (oc < 27) v = mod_w[((oc - 18) * 64 + cin) * 9 + t];
    wA[i] = v;
  } else if (i < 16128 + 36864) {
    int j = i - 16128;
    int oc = j & 63;
    int ck = j >> 6;       // k*64 + c
    int c = ck & 63;
    int k = ck >> 6;
    wB[j] = w[(oc * 64 + c) * 9 + k];
  }
}

// ---------------- kernel A: fused offset + mask conv (3x3, Cin=64 -> 27 ch) ----------------
__global__ __launch_bounds__(256) void convA_kernel(
    const float* __restrict__ x, const float* __restrict__ wA,
    const float* __restrict__ off_b, const float* __restrict__ mod_b,
    float* __restrict__ off_out, float* __restrict__ mask_out) {
  __shared__ float tile[18 * 18];
  int tx = threadIdx.x & 15, ty = threadIdx.x >> 4;
  int tileX = blockIdx.x, tileY = blockIdx.y, bb = blockIdx.z;
  int gx0 = tileX * 16 - 1, gy0 = tileY * 16 - 1;

  float acc[28];
#pragma unroll
  for (int i = 0; i < 28; ++i) acc[i] = 0.f;

  const float4* wA4 = (const float4*)wA;

  for (int cin = 0; cin < Cin; ++cin) {
    const float* xc = x + (((size_t)bb * Cin + cin) << 14);
    __syncthreads();
    for (int i = threadIdx.x; i < 324; i += 256) {
      int r = i / 18;
      int c = i - r * 18;
      int gy = gy0 + r, gx = gx0 + c;
      float v = 0.f;
      if (gy >= 0 && gy < Hn && gx >= 0 && gx < Wn) v = xc[(gy << 7) + gx];
      tile[i] = v;
    }
    __syncthreads();

    float tv[9];
#pragma unroll
    for (int dy = 0; dy < 3; ++dy)
#pragma unroll
      for (int dx = 0; dx < 3; ++dx)
        tv[dy * 3 + dx] = tile[(ty + dy) * 18 + (tx + dx)];

#pragma unroll
    for (int t = 0; t < 9; ++t) {
      const float4* wrow = wA4 + (cin * 9 + t) * 7;
#pragma unroll
      for (int j = 0; j < 7; ++j) {
        float4 wv = wrow[j];
        acc[j * 4 + 0] += tv[t] * wv.x;
        acc[j * 4 + 1] += tv[t] * wv.y;
        acc[j * 4 + 2] += tv[t] * wv.z;
        acc[j * 4 + 3] += tv[t] * wv.w;
      }
    }
  }

  int h = tileY * 16 + ty, wcol = tileX * 16 + tx;
  int hw = (h << 7) + wcol;
#pragma unroll
  for (int oc = 0; oc < 18; ++oc)
    off_out[(((size_t)bb * 18 + oc) << 14) + hw] = acc[oc] + off_b[oc];
#pragma unroll
  for (int j = 0; j < 9; ++j) {
    float z = acc[18 + j] + mod_b[j];
    mask_out[(((size_t)bb * 9 + j) << 14) + hw] = 2.f / (1.f + expf(-z));
  }
}

// ---------------- kernel B: modulated deformable conv ----------------
__global__ __launch_bounds__(256) void deform_kernel(
    const float* __restrict__ x, const float* __restrict__ off,
    const float* __restrict__ mask, const float* __restrict__ wB,
    const float* __restrict__ bias, float* __restrict__ y) {
  int pix = blockIdx.x * 256 + threadIdx.x;   // < 131072
  int bb = pix >> 14;
  int hw = pix & 16383;
  int h = hw >> 7, wcol = hw & 127;

  float acc[64];
#pragma unroll
  for (int i = 0; i < 64; ++i) acc[i] = 0.f;

  const float* xb = x + ((size_t)(bb * Cin) << 14);
  const float4* wB4 = (const float4*)wB;

  for (int k = 0; k < 9; ++k) {
    float dy = off[(((size_t)bb * 18 + 2 * k + 0) << 14) + hw];
    float dx = off[(((size_t)bb * 18 + 2 * k + 1) << 14) + hw];
    float m  = mask[(((size_t)bb * 9 + k) << 14) + hw];

    float py = dy + (float)(h + k / 3 - 1);
    float px = dx + (float)(wcol + k % 3 - 1);
    float y0f = floorf(py), x0f = floorf(px);
    float ly = py - y0f, lx = px - x0f;
    int y0 = (int)y0f, x0 = (int)x0f;
    int y1 = y0 + 1, x1 = x0 + 1;

    float fy0 = (y0 >= 0 && y0 < Hn) ? 1.f : 0.f;
    float fy1 = (y1 >= 0 && y1 < Hn) ? 1.f : 0.f;
    float fx0 = (x0 >= 0 && x0 < Wn) ? 1.f : 0.f;
    float fx1 = (x1 >= 0 && x1 < Wn) ? 1.f : 0.f;

    float w00 = (1.f - ly) * (1.f - lx) * m * fy0 * fx0;
    float w01 = (1.f - ly) * lx         * m * fy0 * fx1;
    float w10 = ly         * (1.f - lx) * m * fy1 * fx0;
    float w11 = ly         * lx         * m * fy1 * fx1;

    int cy0 = min(max(y0, 0), Hn - 1), cy1 = min(max(y1, 0), Hn - 1);
    int cx0 = min(max(x0, 0), Wn - 1), cx1 = min(max(x1, 0), Wn - 1);
    int i00 = (cy0 << 7) + cx0, i01 = (cy0 << 7) + cx1;
    int i10 = (cy1 << 7) + cx0, i11 = (cy1 << 7) + cx1;

    for (int c = 0; c < Cin; ++c) {
      const float* xc = xb + (c << 14);
      float v = w00 * xc[i00] + w01 * xc[i01] + w10 * xc[i10] + w11 * xc[i11];
      const float4* wrow = wB4 + ((k << 6) + c) * 16;
#pragma unroll
      for (int j = 0; j < 16; ++j) {
        float4 wv = wrow[j];
        acc[4 * j + 0] += v * wv.x;
        acc[4 * j + 1] += v * wv.y;
        acc[4 * j + 2] += v * wv.z;
        acc[4 * j + 3] += v * wv.w;
      }
    }
  }

#pragma unroll
  for (int oc = 0; oc < Cout; ++oc)
    y[(((size_t)bb * Cout + oc) << 14) + hw] = acc[oc] + bias[oc];
}

// ---------------- kernel C: per-channel mean/var ----------------
__global__ __launch_bounds__(1024) void stats_kernel(
    const float* __restrict__ y, float* __restrict__ stat) {
  int c = blockIdx.x;
  float s = 0.f, ss = 0.f;
  for (int i = threadIdx.x; i < NPIX; i += 1024) {
    int bb = i >> 14;
    int hw = i & 16383;
    float v = y[(((size_t)bb * Cout + c) << 14) + hw];
    s += v;
    ss += v * v;
  }
#pragma unroll
  for (int o = 32; o > 0; o >>= 1) {
    s += __shfl_xor(s, o);
    ss += __shfl_xor(ss, o);
  }
  __shared__ float shs[16], shss[16];
  int lane = threadIdx.x & 63, wv = threadIdx.x >> 6;
  if (lane == 0) { shs[wv] = s; shss[wv] = ss; }
  __syncthreads();
  if (threadIdx.x == 0) {
    float S = 0.f, SS = 0.f;
#pragma unroll
    for (int i = 0; i < 16; ++i) { S += shs[i]; SS += shss[i]; }
    float mean = S / (float)NPIX;
    float var = SS / (float)NPIX - mean * mean;
    stat[c] = mean;
    stat[64 + c] = var;
  }
}

// ---------------- kernel D: batchnorm scale/shift + relu, in place ----------------
__global__ __launch_bounds__(256) void bnrelu_kernel(
    float* __restrict__ y, const float* __restrict__ stat,
    const float* __restrict__ gamma, const float* __restrict__ beta) {
  int i = blockIdx.x * 256 + threadIdx.x;    // over 2097152 float4s
  int c = (i >> 12) & 63;
  float mean = stat[c], var = stat[64 + c];
  float r = rsqrtf(var + EPSv);
  float g = gamma[c] * r;
  float bt = beta[c] - mean * g;
  float4* y4 = (float4*)y;
  float4 v = y4[i];
  v.x = fmaxf(v.x * g + bt, 0.f);
  v.y = fmaxf(v.y * g + bt, 0.f);
  v.z = fmaxf(v.z * g + bt, 0.f);
  v.w = fmaxf(v.w * g + bt, 0.f);
  y4[i] = v;
}

extern "C" void kernel_launch(void* const* d_in, const int* in_sizes, int n_in,
                              void* d_out, int out_size, void* d_ws, size_t ws_size,
                              hipStream_t stream) {
  const float* x     = (const float*)d_in[0];
  const float* off_w = (const float*)d_in[1];
  const float* off_b = (const float*)d_in[2];
  const float* mod_w = (const float*)d_in[3];
  const float* mod_b = (const float*)d_in[4];
  const float* w     = (const float*)d_in[5];
  const float* b     = (const float*)d_in[6];
  const float* gamma = (const float*)d_in[7];
  const float* beta  = (const float*)d_in[8];
  float* out = (float*)d_out;
  float* ws  = (float*)d_ws;

  float* offo  = ws + OFF_OFF;
  float* masko = ws + MASK_OFF;
  float* wA    = ws + WA_OFF;
  float* wB    = ws + WB_OFF;
  float* stat  = ws + STAT_OFF;

  prep_kernel<<<(16128 + 36864 + 255) / 256, 256, 0, stream>>>(off_w, mod_w, w, wA, wB);
  convA_kernel<<<dim3(8, 8, 8), 256, 0, stream>>>(x, wA, off_b, mod_b, offo, masko);
  deform_kernel<<<NPIX / 256, 256, 0, stream>>>(x, offo, masko, wB, b, out);
  stats_kernel<<<64, 1024, 0, stream>>>(out, stat);
  bnrelu_kernel<<<(NPIX * Cout / 4) / 256, 256, 0, stream>>>(out, gamma ? stat : stat, gamma, beta);
}

// Round 2
// 565.968 us; speedup vs baseline: 1.0053x; 1.0053x over previous
//
#include <hip/hip_runtime.h>
#include <math.h>

// Problem constants: B=8, C=64 (in), OC=64 (out), H=W=128, K=3x3=9, PAD=1.
#define Bn 8
#define Cin 64
#define Cout 64
#define Hn 128
#define Wn 128
#define HW 16384          // H*W
#define NPIX 131072       // B*H*W
#define EPSv 1e-5f

// ws layout (floats)
#define OFF_OFF  0                       // 8*18*16384 = 2359296
#define MASK_OFF 2359296                 // 8*9*16384  = 1179648
#define WA_OFF   3538944                 // 64*9*28    = 16128  (conv weights, [cin][t][oc'] oc' padded to 28)
#define WBT_OFF  3555072                 // 9*64*64 bf16 = 36864 shorts (fits in 18432 floats)
#define STAT_OFF 3591936                 // 128 (mean[64], var[64])

typedef short s16x8 __attribute__((ext_vector_type(8)));
typedef float f32x4 __attribute__((ext_vector_type(4)));

__device__ __forceinline__ unsigned short f2bf(float f) {
  unsigned u = __float_as_uint(f);
  unsigned r = (u + 0x7fffu + ((u >> 16) & 1u)) >> 16;   // RNE
  return (unsigned short)r;
}

// ---------------- prep: reorder weights ----------------
__global__ __launch_bounds__(256) void prep_kernel(
    const float* __restrict__ off_w, const float* __restrict__ mod_w,
    const float* __restrict__ w, float* __restrict__ wA, unsigned short* __restrict__ wbt) {
  int i = blockIdx.x * 256 + threadIdx.x;
  if (i < 16128) {
    // wA[(cin*9 + t)*28 + oc'], oc'<18 -> off_w[oc'][cin][t], 18..26 -> mod_w[oc'-18][cin][t], 27 -> 0
    int oc = i % 28;
    int rt = i / 28;
    int t = rt % 9;
    int cin = rt / 9;
    float v = 0.f;
    if (oc < 18) v = off_w[(oc * 64 + cin) * 9 + t];
    else if (oc < 27) v = mod_w[((oc - 18) * 64 + cin) * 9 + t];
    wA[i] = v;
  } else if (i < 16128 + 36864) {
    // wbt[k][oc][c] bf16  (A-operand: rows of 64 contiguous c per oc)
    int j = i - 16128;
    int c = j & 63;
    int oc = (j >> 6) & 63;
    int k = j >> 12;
    wbt[j] = f2bf(w[(oc * 64 + c) * 9 + k]);
  }
}

// ---------------- kernel A: fused offset + mask conv (3x3, Cin=64 -> 27 ch) ----------------
__global__ __launch_bounds__(256) void convA_kernel(
    const float* __restrict__ x, const float* __restrict__ wA,
    const float* __restrict__ off_b, const float* __restrict__ mod_b,
    float* __restrict__ off_out, float* __restrict__ mask_out) {
  __shared__ float tile[18 * 18];
  int tx = threadIdx.x & 15, ty = threadIdx.x >> 4;
  int tileX = blockIdx.x, tileY = blockIdx.y, bb = blockIdx.z;
  int gx0 = tileX * 16 - 1, gy0 = tileY * 16 - 1;

  float acc[28];
#pragma unroll
  for (int i = 0; i < 28; ++i) acc[i] = 0.f;

  const float4* wA4 = (const float4*)wA;

  for (int cin = 0; cin < Cin; ++cin) {
    const float* xc = x + (((size_t)bb * Cin + cin) << 14);
    __syncthreads();
    for (int i = threadIdx.x; i < 324; i += 256) {
      int r = i / 18;
      int c = i - r * 18;
      int gy = gy0 + r, gx = gx0 + c;
      float v = 0.f;
      if (gy >= 0 && gy < Hn && gx >= 0 && gx < Wn) v = xc[(gy << 7) + gx];
      tile[i] = v;
    }
    __syncthreads();

    float tv[9];
#pragma unroll
    for (int dy = 0; dy < 3; ++dy)
#pragma unroll
      for (int dx = 0; dx < 3; ++dx)
        tv[dy * 3 + dx] = tile[(ty + dy) * 18 + (tx + dx)];

#pragma unroll
    for (int t = 0; t < 9; ++t) {
      const float4* wrow = wA4 + (cin * 9 + t) * 7;
#pragma unroll
      for (int j = 0; j < 7; ++j) {
        float4 wv = wrow[j];
        acc[j * 4 + 0] += tv[t] * wv.x;
        acc[j * 4 + 1] += tv[t] * wv.y;
        acc[j * 4 + 2] += tv[t] * wv.z;
        acc[j * 4 + 3] += tv[t] * wv.w;
      }
    }
  }

  int h = tileY * 16 + ty, wcol = tileX * 16 + tx;
  int hw = (h << 7) + wcol;
#pragma unroll
  for (int oc = 0; oc < 18; ++oc)
    off_out[(((size_t)bb * 18 + oc) << 14) + hw] = acc[oc] + off_b[oc];
#pragma unroll
  for (int j = 0; j < 9; ++j) {
    float z = acc[18 + j] + mod_b[j];
    mask_out[(((size_t)bb * 9 + j) << 14) + hw] = 2.f / (1.f + expf(-z));
  }
}

// ---------------- kernel B: modulated deformable conv via MFMA implicit GEMM ----------------
// Block = one (b,h) image row (128 pixels). GEMM: D[64 oc][128 pix] += W[oc][c] * V[c][pix]
// per tap k, contracting c in two 32-chunks with mfma_f32_16x16x32_bf16.
// LDS layouts (row stride 72 bf16 = 36 words: lanes spread across all 32 banks at the
// b128 floor): vlds[pix][c] (B-operand: 8 consecutive c per lane), wlds[oc][c] (A-operand).
__global__ __launch_bounds__(256, 4) void deform_mfma_kernel(
    const float* __restrict__ x, const float* __restrict__ off,
    const float* __restrict__ mask, const unsigned short* __restrict__ wbt,
    const float* __restrict__ bias, float* __restrict__ y) {
  __shared__ short vlds[128 * 72];   // 18432 B
  __shared__ short wlds[64 * 72];    // 9216 B
  int t = threadIdx.x;
  int bh = blockIdx.x;
  int b = bh >> 7, h = bh & 127;
  int p = t & 127;          // pixel (w coordinate) this thread builds v for
  int half = t >> 7;        // which 32-channel half this thread builds
  int ln = t & 15;          // lane&15
  int quad = (t >> 4) & 3;  // lane>>4
  int wv = t >> 6;          // wave id: pixels [wv*32, wv*32+32)
  int hw = h << 7;

  f32x4 acc[4][2];
#pragma unroll
  for (int mt = 0; mt < 4; ++mt)
#pragma unroll
    for (int nt = 0; nt < 2; ++nt)
      acc[mt][nt] = (f32x4){0.f, 0.f, 0.f, 0.f};

  const float* xbase = x + ((size_t)((b << 6) + (half << 5)) << 14);

  for (int k = 0; k < 9; ++k) {
    // per-pixel bilinear setup (2 threads per pixel duplicate this; cheap)
    int obase = ((b * 18 + 2 * k) << 14) + hw + p;
    float dy = off[obase];
    float dx = off[obase + HW];
    float m = mask[((b * 9 + k) << 14) + hw + p];
    float py = dy + (float)(h + k / 3 - 1);
    float px = dx + (float)(p + (k % 3) - 1);
    float y0f = floorf(py), x0f = floorf(px);
    float ly = py - y0f, lx = px - x0f;
    int y0 = (int)y0f, x0i = (int)x0f;
    int y1 = y0 + 1, x1 = x0i + 1;
    float fy0 = (y0 >= 0 && y0 < Hn) ? 1.f : 0.f;
    float fy1 = (y1 >= 0 && y1 < Hn) ? 1.f : 0.f;
    float fx0 = (x0i >= 0 && x0i < Wn) ? 1.f : 0.f;
    float fx1 = (x1 >= 0 && x1 < Wn) ? 1.f : 0.f;
    float w00 = (1.f - ly) * (1.f - lx) * m * fy0 * fx0;
    float w01 = (1.f - ly) * lx * m * fy0 * fx1;
    float w10 = ly * (1.f - lx) * m * fy1 * fx0;
    float w11 = ly * lx * m * fy1 * fx1;
    int cy0 = min(max(y0, 0), Hn - 1), cy1 = min(max(y1, 0), Hn - 1);
    int cx0 = min(max(x0i, 0), Wn - 1), cx1 = min(max(x1, 0), Wn - 1);
    int i00 = (cy0 << 7) + cx0, i01 = (cy0 << 7) + cx1;
    int i10 = (cy1 << 7) + cx0, i11 = (cy1 << 7) + cx1;

    __syncthreads();   // previous k's MFMA reads of vlds/wlds complete

    // stage W[oc][c] for this tap: thread t -> oc=t>>2, 16 c at (t&3)*16
    {
      const s16x8* src = (const s16x8*)(wbt + (((k << 6) + (t >> 2)) << 6) + ((t & 3) << 4));
      s16x8 w0 = src[0];
      s16x8 w1 = src[1];
      short* dst = wlds + (t >> 2) * 72 + ((t & 3) << 4);
      *(s16x8*)dst = w0;
      *(s16x8*)(dst + 8) = w1;
    }

    // build v for 32 channels of this pixel, pack to bf16
    s16x8 pkv[4];
#pragma unroll
    for (int g = 0; g < 4; ++g) {
#pragma unroll
      for (int j = 0; j < 8; ++j) {
        const float* xc = xbase + (((g << 3) + j) << 14);
        float v = w00 * xc[i00] + w01 * xc[i01] + w10 * xc[i10] + w11 * xc[i11];
        pkv[g][j] = (short)f2bf(v);
      }
    }
    short* vd = vlds + p * 72 + (half << 5);
    *(s16x8*)(vd + 0) = pkv[0];
    *(s16x8*)(vd + 8) = pkv[1];
    *(s16x8*)(vd + 16) = pkv[2];
    *(s16x8*)(vd + 24) = pkv[3];

    __syncthreads();   // vlds/wlds ready

#pragma unroll
    for (int chunk = 0; chunk < 2; ++chunk) {
      s16x8 bfr0 = *(const s16x8*)(vlds + ((wv << 5) + ln) * 72 + (chunk << 5) + (quad << 3));
      s16x8 bfr1 = *(const s16x8*)(vlds + ((wv << 5) + 16 + ln) * 72 + (chunk << 5) + (quad << 3));
#pragma unroll
      for (int mt = 0; mt < 4; ++mt) {
        s16x8 afr = *(const s16x8*)(wlds + ((mt << 4) + ln) * 72 + (chunk << 5) + (quad << 3));
        acc[mt][0] = __builtin_amdgcn_mfma_f32_16x16x32_bf16(afr, bfr0, acc[mt][0], 0, 0, 0);
        acc[mt][1] = __builtin_amdgcn_mfma_f32_16x16x32_bf16(afr, bfr1, acc[mt][1], 0, 0, 0);
      }
    }
  }

  // epilogue: D row = oc = mt*16 + quad*4 + r, col = pix = wv*32 + nt*16 + ln
#pragma unroll
  for (int mt = 0; mt < 4; ++mt) {
#pragma unroll
    for (int r = 0; r < 4; ++r) {
      int oc = (mt << 4) + (quad << 2) + r;
      float bv = bias[oc];
      float* yp = y + (((size_t)(b << 6) + oc) << 14) + hw;
      yp[(wv << 5) + ln] = acc[mt][0][r] + bv;
      yp[(wv << 5) + 16 + ln] = acc[mt][1][r] + bv;
    }
  }
}

// ---------------- kernel C: per-channel mean/var ----------------
__global__ __launch_bounds__(1024) void stats_kernel(
    const float* __restrict__ y, float* __restrict__ stat) {
  int c = blockIdx.x;
  float s = 0.f, ss = 0.f;
  for (int i = threadIdx.x; i < NPIX; i += 1024) {
    int bb = i >> 14;
    int hw = i & 16383;
    float v = y[(((size_t)bb * Cout + c) << 14) + hw];
    s += v;
    ss += v * v;
  }
#pragma unroll
  for (int o = 32; o > 0; o >>= 1) {
    s += __shfl_xor(s, o);
    ss += __shfl_xor(ss, o);
  }
  __shared__ float shs[16], shss[16];
  int lane = threadIdx.x & 63, wv = threadIdx.x >> 6;
  if (lane == 0) { shs[wv] = s; shss[wv] = ss; }
  __syncthreads();
  if (threadIdx.x == 0) {
    float S = 0.f, SS = 0.f;
#pragma unroll
    for (int i = 0; i < 16; ++i) { S += shs[i]; SS += shss[i]; }
    float mean = S / (float)NPIX;
    float var = SS / (float)NPIX - mean * mean;
    stat[c] = mean;
    stat[64 + c] = var;
  }
}

// ---------------- kernel D: batchnorm scale/shift + relu, in place ----------------
__global__ __launch_bounds__(256) void bnrelu_kernel(
    float* __restrict__ y, const float* __restrict__ stat,
    const float* __restrict__ gamma, const float* __restrict__ beta) {
  int i = blockIdx.x * 256 + threadIdx.x;    // over 2097152 float4s
  int c = (i >> 12) & 63;
  float mean = stat[c], var = stat[64 + c];
  float r = rsqrtf(var + EPSv);
  float g = gamma[c] * r;
  float bt = beta[c] - mean * g;
  float4* y4 = (float4*)y;
  float4 v = y4[i];
  v.x = fmaxf(v.x * g + bt, 0.f);
  v.y = fmaxf(v.y * g + bt, 0.f);
  v.z = fmaxf(v.z * g + bt, 0.f);
  v.w = fmaxf(v.w * g + bt, 0.f);
  y4[i] = v;
}

extern "C" void kernel_launch(void* const* d_in, const int* in_sizes, int n_in,
                              void* d_out, int out_size, void* d_ws, size_t ws_size,
                              hipStream_t stream) {
  const float* x     = (const float*)d_in[0];
  const float* off_w = (const float*)d_in[1];
  const float* off_b = (const float*)d_in[2];
  const float* mod_w = (const float*)d_in[3];
  const float* mod_b = (const float*)d_in[4];
  const float* w     = (const float*)d_in[5];
  const float* b     = (const float*)d_in[6];
  const float* gamma = (const float*)d_in[7];
  const float* beta  = (const float*)d_in[8];
  float* out = (float*)d_out;
  float* ws  = (float*)d_ws;

  float* offo  = ws + OFF_OFF;
  float* masko = ws + MASK_OFF;
  float* wA    = ws + WA_OFF;
  unsigned short* wbt = (unsigned short*)(ws + WBT_OFF);
  float* stat  = ws + STAT_OFF;

  prep_kernel<<<(16128 + 36864 + 255) / 256, 256, 0, stream>>>(off_w, mod_w, w, wA, wbt);
  convA_kernel<<<dim3(8, 8, 8), 256, 0, stream>>>(x, wA, off_b, mod_b, offo, masko);
  deform_mfma_kernel<<<1024, 256, 0, stream>>>(x, offo, masko, wbt, b, out);
  stats_kernel<<<64, 1024, 0, stream>>>(out, stat);
  bnrelu_kernel<<<(NPIX * Cout / 4) / 256, 256, 0, stream>>>(out, stat, gamma, beta);
}

// Round 4
// 335.282 us; speedup vs baseline: 1.6970x; 1.6880x over previous
//
#include <hip/hip_runtime.h>
#include <math.h>

// Problem constants: B=8, C=64 (in), OC=64 (out), H=W=128, K=3x3=9, PAD=1.
#define Hn 128
#define Wn 128
#define HW 16384
#define NPIX 131072
#define EPSv 1e-5f

// ws layout (floats)
#define OFF_OFF  0            // 8*18*16384 = 2359296
#define MASK_OFF 2359296      // 8*9*16384  = 1179648
#define WBTA_OFF 3538944      // 20480 shorts (convA weights, [it(20)][oc(32)][e(32)]) = 10240 floats
#define WBTB_OFF 3549184      // 40960 shorts (deform weights, [it(20)][oc(64)][e(32)]) = 20480 floats
#define STAT_OFF 3569664      // 128 (sum[64], sumsq[64])

// K-packing: 640 = 4 c16-chunks x 5 tap-pairs x 32. K-elem e in [0,32):
//   tap = tp*2 + (e>>4)  (tap 9 = zero pad), c = chunk*16 + (e&15).
// it = chunk*5 + tp, chunk OUTER (x L1 reuse across taps), tp inner.

typedef short s16x8 __attribute__((ext_vector_type(8)));
typedef float f32x4 __attribute__((ext_vector_type(4)));

__device__ __forceinline__ unsigned short f2bf(float f) {
  unsigned u = __float_as_uint(f);
  return (unsigned short)((u + 0x7fffu + ((u >> 16) & 1u)) >> 16);  // RNE
}

// ---------------- prep: pack weights into MFMA A-operand order; zero stat ----------------
__global__ __launch_bounds__(256) void prep_kernel(
    const float* __restrict__ off_w, const float* __restrict__ mod_w,
    const float* __restrict__ w, unsigned short* __restrict__ wbtA,
    unsigned short* __restrict__ wbtB, float* __restrict__ stat) {
  int i = blockIdx.x * 256 + threadIdx.x;
  if (i < 128) stat[i] = 0.f;
  if (i < 20480) {
    int e = i & 31, oc = (i >> 5) & 31, it = i >> 10;
    int tp = it % 5, chunk = it / 5;
    int tap = tp * 2 + (e >> 4);
    int c = (chunk << 4) + (e & 15);
    float v = 0.f;
    if (tap < 9) {
      if (oc < 18) v = off_w[(oc * 64 + c) * 9 + tap];
      else if (oc < 27) v = mod_w[((oc - 18) * 64 + c) * 9 + tap];
    }
    wbtA[i] = f2bf(v);
  } else if (i < 20480 + 40960) {
    int j = i - 20480;
    int e = j & 31, oc = (j >> 5) & 63, it = j >> 11;
    int tp = it % 5, chunk = it / 5;
    int tap = tp * 2 + (e >> 4);
    int c = (chunk << 4) + (e & 15);
    float v = (tap < 9) ? w[(oc * 64 + c) * 9 + tap] : 0.f;
    wbtB[j] = f2bf(v);
  }
}

// ---------------- kernel A: offset+mask conv as implicit-GEMM MFMA (M=32 incl pad) ----------------
// Block = one (b,h) row, 256 threads. XCD swizzle: b = blockIdx.x & 7.
__global__ __launch_bounds__(256, 4) void convA_mfma_kernel(
    const float* __restrict__ x, const unsigned short* __restrict__ wbtA,
    const float* __restrict__ off_b, const float* __restrict__ mod_b,
    float* __restrict__ off_out, float* __restrict__ mask_out) {
  __shared__ short vlds[2 * 128 * 40];   // double-buffered, row stride 40 (80 B: 2-way banks, free)
  int t = threadIdx.x;
  int bx = blockIdx.x;
  int b = bx & 7, h = bx >> 3;
  int p = t & 127, half = t >> 7;
  int ln = t & 15, quad = (t >> 4) & 3, wv = t >> 6;

  f32x4 acc[2][2];
#pragma unroll
  for (int mt = 0; mt < 2; ++mt)
#pragma unroll
    for (int nt = 0; nt < 2; ++nt) acc[mt][nt] = (f32x4){0.f, 0.f, 0.f, 0.f};

  const float* xb = x + ((size_t)(b << 6) << 14);

  for (int it = 0; it < 20; ++it) {
    int chunk = it / 5, tp = it - chunk * 5;
    const float* xc0 = xb + ((size_t)((chunk << 4) + (half << 3)) << 14);
    s16x8 pk[2];
#pragma unroll
    for (int s = 0; s < 2; ++s) {
      int tap = tp * 2 + s;
      if (tap < 9) {
        int gy = h + tap / 3 - 1;
        int gx = p + tap % 3 - 1;
        bool ok = (gy >= 0) && (gy < Hn) && (gx >= 0) && (gx < Wn);
        int idx = ok ? ((gy << 7) + gx) : 0;
#pragma unroll
        for (int j = 0; j < 8; ++j) {
          float vv = ok ? xc0[(j << 14) + idx] : 0.f;
          pk[s][j] = (short)f2bf(vv);
        }
      } else {
#pragma unroll
        for (int j = 0; j < 8; ++j) pk[s][j] = 0;
      }
    }
    short* vd = vlds + (it & 1) * 5120 + p * 40 + (half << 3);
    *(s16x8*)(vd) = pk[0];
    *(s16x8*)(vd + 16) = pk[1];
    __syncthreads();
    const short* vb = vlds + (it & 1) * 5120;
    s16x8 B0 = *(const s16x8*)(vb + ((wv << 5) + ln) * 40 + (quad << 3));
    s16x8 B1 = *(const s16x8*)(vb + ((wv << 5) + 16 + ln) * 40 + (quad << 3));
#pragma unroll
    for (int mt = 0; mt < 2; ++mt) {
      s16x8 A = *(const s16x8*)(wbtA + (size_t)((it << 5) + (mt << 4) + ln) * 32 + (quad << 3));
      acc[mt][0] = __builtin_amdgcn_mfma_f32_16x16x32_bf16(A, B0, acc[mt][0], 0, 0, 0);
      acc[mt][1] = __builtin_amdgcn_mfma_f32_16x16x32_bf16(A, B1, acc[mt][1], 0, 0, 0);
    }
  }

  int hw = h << 7;
#pragma unroll
  for (int mt = 0; mt < 2; ++mt)
#pragma unroll
    for (int r = 0; r < 4; ++r) {
      int oc = (mt << 4) + (quad << 2) + r;
#pragma unroll
      for (int nt = 0; nt < 2; ++nt) {
        int px = (wv << 5) + (nt << 4) + ln;
        float val = acc[mt][nt][r];
        if (oc < 18) {
          off_out[(((size_t)b * 18 + oc) << 14) + hw + px] = val + off_b[oc];
        } else if (oc < 27) {
          float z = val + mod_b[oc - 18];
          mask_out[(((size_t)b * 9 + (oc - 18)) << 14) + hw + px] = 2.f / (1.f + expf(-z));
        }
      }
    }
}

// ---------------- kernel B: modulated deformable conv as implicit-GEMM MFMA (M=64) ----------------
__global__ __launch_bounds__(256, 4) void deform_mfma_kernel(
    const float* __restrict__ x, const float* __restrict__ off,
    const float* __restrict__ mask, const unsigned short* __restrict__ wbtB,
    const float* __restrict__ bias, float* __restrict__ y) {
  __shared__ short vlds[2 * 128 * 40];
  int t = threadIdx.x;
  int bx = blockIdx.x;
  int b = bx & 7, h = bx >> 3;
  int p = t & 127, half = t >> 7;
  int ln = t & 15, quad = (t >> 4) & 3, wv = t >> 6;
  int hw = h << 7;

  f32x4 acc[4][2];
#pragma unroll
  for (int mt = 0; mt < 4; ++mt)
#pragma unroll
    for (int nt = 0; nt < 2; ++nt) acc[mt][nt] = (f32x4){0.f, 0.f, 0.f, 0.f};

  const float* xb = x + ((size_t)(b << 6) << 14);

  for (int it = 0; it < 20; ++it) {
    int chunk = it / 5, tp = it - chunk * 5;
    const float* xc0 = xb + ((size_t)((chunk << 4) + (half << 3)) << 14);
    s16x8 pk[2];
#pragma unroll
    for (int s = 0; s < 2; ++s) {
      int tap = tp * 2 + s;
      if (tap < 9) {
        int ob = ((b * 18 + 2 * tap) << 14) + hw + p;
        float dy = off[ob];
        float dx = off[ob + HW];
        float m = mask[((b * 9 + tap) << 14) + hw + p];
        float py = dy + (float)(h + tap / 3 - 1);
        float pxf = dx + (float)(p + tap % 3 - 1);
        float y0f = floorf(py), x0f = floorf(pxf);
        float ly = py - y0f, lx = pxf - x0f;
        int y0 = (int)y0f, x0 = (int)x0f;
        int y1 = y0 + 1, x1 = x0 + 1;
        float fy0 = (y0 >= 0 && y0 < Hn) ? 1.f : 0.f;
        float fy1 = (y1 >= 0 && y1 < Hn) ? 1.f : 0.f;
        float fx0 = (x0 >= 0 && x0 < Wn) ? 1.f : 0.f;
        float fx1 = (x1 >= 0 && x1 < Wn) ? 1.f : 0.f;
        float w00 = (1.f - ly) * (1.f - lx) * m * fy0 * fx0;
        float w01 = (1.f - ly) * lx * m * fy0 * fx1;
        float w10 = ly * (1.f - lx) * m * fy1 * fx0;
        float w11 = ly * lx * m * fy1 * fx1;
        int cy0 = min(max(y0, 0), Hn - 1), cy1 = min(max(y1, 0), Hn - 1);
        int cx0 = min(max(x0, 0), Wn - 1), cx1 = min(max(x1, 0), Wn - 1);
        int i00 = (cy0 << 7) + cx0, i01 = (cy0 << 7) + cx1;
        int i10 = (cy1 << 7) + cx0, i11 = (cy1 << 7) + cx1;
#pragma unroll
        for (int j = 0; j < 8; ++j) {
          const float* xc = xc0 + (j << 14);
          float v = w00 * xc[i00] + w01 * xc[i01] + w10 * xc[i10] + w11 * xc[i11];
          pk[s][j] = (short)f2bf(v);
        }
      } else {
#pragma unroll
        for (int j = 0; j < 8; ++j) pk[s][j] = 0;
      }
    }
    short* vd = vlds + (it & 1) * 5120 + p * 40 + (half << 3);
    *(s16x8*)(vd) = pk[0];
    *(s16x8*)(vd + 16) = pk[1];
    __syncthreads();
    const short* vb = vlds + (it & 1) * 5120;
    s16x8 B0 = *(const s16x8*)(vb + ((wv << 5) + ln) * 40 + (quad << 3));
    s16x8 B1 = *(const s16x8*)(vb + ((wv << 5) + 16 + ln) * 40 + (quad << 3));
#pragma unroll
    for (int mt = 0; mt < 4; ++mt) {
      s16x8 A = *(const s16x8*)(wbtB + (size_t)((it << 6) + (mt << 4) + ln) * 32 + (quad << 3));
      acc[mt][0] = __builtin_amdgcn_mfma_f32_16x16x32_bf16(A, B0, acc[mt][0], 0, 0, 0);
      acc[mt][1] = __builtin_amdgcn_mfma_f32_16x16x32_bf16(A, B1, acc[mt][1], 0, 0, 0);
    }
  }

#pragma unroll
  for (int mt = 0; mt < 4; ++mt)
#pragma unroll
    for (int r = 0; r < 4; ++r) {
      int oc = (mt << 4) + (quad << 2) + r;
      float bv = bias[oc];
      float* yp = y + (((size_t)(b << 6) + oc) << 14) + hw;
      yp[(wv << 5) + ln] = acc[mt][0][r] + bv;
      yp[(wv << 5) + 16 + ln] = acc[mt][1][r] + bv;
    }
}

// ---------------- kernel C: per-channel sum/sumsq (sliced, atomics into stat) ----------------
__global__ __launch_bounds__(256) void stats2_kernel(
    const float* __restrict__ y, float* __restrict__ stat) {
  int bxx = blockIdx.x;            // 1024 = 64 ch x 16 slices
  int c = bxx & 63, sl = bxx >> 6;
  int bb = sl >> 1;
  const float4* yp = (const float4*)(y + (((size_t)bb * 64 + c) << 14) + ((sl & 1) << 13));
  float s = 0.f, ss = 0.f;
  for (int i = threadIdx.x; i < 2048; i += 256) {
    float4 v = yp[i];
    s += v.x + v.y + v.z + v.w;
    ss += v.x * v.x + v.y * v.y + v.z * v.z + v.w * v.w;
  }
#pragma unroll
  for (int o = 32; o > 0; o >>= 1) {
    s += __shfl_xor(s, o);
    ss += __shfl_xor(ss, o);
  }
  __shared__ float shs[4], shss[4];
  int lane = threadIdx.x & 63, wv = threadIdx.x >> 6;
  if (lane == 0) { shs[wv] = s; shss[wv] = ss; }
  __syncthreads();
  if (threadIdx.x == 0) {
    float S = shs[0] + shs[1] + shs[2] + shs[3];
    float SS = shss[0] + shss[1] + shss[2] + shss[3];
    atomicAdd(stat + c, S);
    atomicAdd(stat + 64 + c, SS);
  }
}

// ---------------- kernel D: batchnorm scale/shift + relu, in place ----------------
// R3 BUG WAS HERE: launched with 2048 blocks but needs 8192 for 2097152 float4s.
// Now grid-stride so coverage is correct for any grid >= 1.
__global__ __launch_bounds__(256) void bnrelu_kernel(
    float* __restrict__ y, const float* __restrict__ stat,
    const float* __restrict__ gamma, const float* __restrict__ beta) {
  float4* y4 = (float4*)y;
  for (int i = blockIdx.x * 256 + threadIdx.x; i < 2097152; i += gridDim.x * 256) {
    int c = (i >> 12) & 63;
    float mean = stat[c] * (1.f / (float)NPIX);
    float var = stat[64 + c] * (1.f / (float)NPIX) - mean * mean;
    float r = rsqrtf(var + EPSv);
    float g = gamma[c] * r;
    float bt = beta[c] - mean * g;
    float4 v = y4[i];
    v.x = fmaxf(v.x * g + bt, 0.f);
    v.y = fmaxf(v.y * g + bt, 0.f);
    v.z = fmaxf(v.z * g + bt, 0.f);
    v.w = fmaxf(v.w * g + bt, 0.f);
    y4[i] = v;
  }
}

extern "C" void kernel_launch(void* const* d_in, const int* in_sizes, int n_in,
                              void* d_out, int out_size, void* d_ws, size_t ws_size,
                              hipStream_t stream) {
  const float* x     = (const float*)d_in[0];
  const float* off_w = (const float*)d_in[1];
  const float* off_b = (const float*)d_in[2];
  const float* mod_w = (const float*)d_in[3];
  const float* mod_b = (const float*)d_in[4];
  const float* w     = (const float*)d_in[5];
  const float* b     = (const float*)d_in[6];
  const float* gamma = (const float*)d_in[7];
  const float* beta  = (const float*)d_in[8];
  float* out = (float*)d_out;
  float* ws  = (float*)d_ws;

  float* offo  = ws + OFF_OFF;
  float* masko = ws + MASK_OFF;
  unsigned short* wbtA = (unsigned short*)(ws + WBTA_OFF);
  unsigned short* wbtB = (unsigned short*)(ws + WBTB_OFF);
  float* stat  = ws + STAT_OFF;

  prep_kernel<<<240, 256, 0, stream>>>(off_w, mod_w, w, wbtA, wbtB, stat);
  convA_mfma_kernel<<<1024, 256, 0, stream>>>(x, wbtA, off_b, mod_b, offo, masko);
  deform_mfma_kernel<<<1024, 256, 0, stream>>>(x, offo, masko, wbtB, b, out);
  stats2_kernel<<<1024, 256, 0, stream>>>(out, stat);
  bnrelu_kernel<<<8192, 256, 0, stream>>>(out, stat, gamma, beta);
}

// Round 5
// 331.991 us; speedup vs baseline: 1.7138x; 1.0099x over previous
//
#include <hip/hip_runtime.h>
#include <math.h>

// Problem constants: B=8, C=64 (in), OC=64 (out), H=W=128, K=3x3=9, PAD=1.
#define Hn 128
#define Wn 128
#define HW 16384
#define NPIX 131072
#define EPSv 1e-5f

// ws layout (floats)
#define OFF_OFF  0            // 8*18*16384 = 2359296
#define MASK_OFF 2359296      // 8*9*16384  = 1179648
#define WBTA_OFF 3538944      // 20480 shorts (convA weights, [it(20)][oc(32)][e(32)]) = 10240 floats
#define WBTB_OFF 3549184      // 40960 shorts (deform weights, [it(20)][oc(64)][e(32)]) = 20480 floats
#define STAT_OFF 3569664      // 128 (sum[64], sumsq[64])

// K-packing: 640 = 4 c16-chunks x 5 tap-pairs x 32. K-elem e in [0,32):
//   tap = tp*2 + (e>>4)  (tap 9 = zero pad), c = chunk*16 + (e&15).
// it = chunk*5 + tp, chunk OUTER (x L1 reuse across taps), tp inner.

typedef short s16x8 __attribute__((ext_vector_type(8)));
typedef unsigned short u16x4 __attribute__((ext_vector_type(4)));
typedef float f32x4 __attribute__((ext_vector_type(4)));

__device__ __forceinline__ unsigned short f2bf(float f) {
  unsigned u = __float_as_uint(f);
  return (unsigned short)((u + 0x7fffu + ((u >> 16) & 1u)) >> 16);  // RNE
}
__device__ __forceinline__ float bf2f(unsigned short s) {
  return __uint_as_float((unsigned)s << 16);
}

// ---------------- prep: pack weights into MFMA A-operand order; zero stat ----------------
__global__ __launch_bounds__(256) void prep_kernel(
    const float* __restrict__ off_w, const float* __restrict__ mod_w,
    const float* __restrict__ w, unsigned short* __restrict__ wbtA,
    unsigned short* __restrict__ wbtB, float* __restrict__ stat) {
  int i = blockIdx.x * 256 + threadIdx.x;
  if (i < 128) stat[i] = 0.f;
  if (i < 20480) {
    int e = i & 31, oc = (i >> 5) & 31, it = i >> 10;
    int tp = it % 5, chunk = it / 5;
    int tap = tp * 2 + (e >> 4);
    int c = (chunk << 4) + (e & 15);
    float v = 0.f;
    if (tap < 9) {
      if (oc < 18) v = off_w[(oc * 64 + c) * 9 + tap];
      else if (oc < 27) v = mod_w[((oc - 18) * 64 + c) * 9 + tap];
    }
    wbtA[i] = f2bf(v);
  } else if (i < 20480 + 40960) {
    int j = i - 20480;
    int e = j & 31, oc = (j >> 5) & 63, it = j >> 11;
    int tp = it % 5, chunk = it / 5;
    int tap = tp * 2 + (e >> 4);
    int c = (chunk << 4) + (e & 15);
    float v = (tap < 9) ? w[(oc * 64 + c) * 9 + tap] : 0.f;
    wbtB[j] = f2bf(v);
  }
}

// ---------------- kernel A: offset+mask conv as implicit-GEMM MFMA (M=32 incl pad) ----------------
// Block = one (b,h) row, 256 threads. XCD swizzle: b = blockIdx.x & 7.
__global__ __launch_bounds__(256, 4) void convA_mfma_kernel(
    const float* __restrict__ x, const unsigned short* __restrict__ wbtA,
    const float* __restrict__ off_b, const float* __restrict__ mod_b,
    float* __restrict__ off_out, float* __restrict__ mask_out) {
  __shared__ short vlds[2 * 128 * 40];   // double-buffered, row stride 40 (80 B: 2-way banks, free)
  int t = threadIdx.x;
  int bx = blockIdx.x;
  int b = bx & 7, h = bx >> 3;
  int p = t & 127, half = t >> 7;
  int ln = t & 15, quad = (t >> 4) & 3, wv = t >> 6;

  f32x4 acc[2][2];
#pragma unroll
  for (int mt = 0; mt < 2; ++mt)
#pragma unroll
    for (int nt = 0; nt < 2; ++nt) acc[mt][nt] = (f32x4){0.f, 0.f, 0.f, 0.f};

  const float* xb = x + ((size_t)(b << 6) << 14);

  for (int it = 0; it < 20; ++it) {
    int chunk = it / 5, tp = it - chunk * 5;
    const float* xc0 = xb + ((size_t)((chunk << 4) + (half << 3)) << 14);
    s16x8 pk[2];
#pragma unroll
    for (int s = 0; s < 2; ++s) {
      int tap = tp * 2 + s;
      if (tap < 9) {
        int gy = h + tap / 3 - 1;
        int gx = p + tap % 3 - 1;
        bool ok = (gy >= 0) && (gy < Hn) && (gx >= 0) && (gx < Wn);
        int idx = ok ? ((gy << 7) + gx) : 0;
#pragma unroll
        for (int j = 0; j < 8; ++j) {
          float vv = ok ? xc0[(j << 14) + idx] : 0.f;
          pk[s][j] = (short)f2bf(vv);
        }
      } else {
#pragma unroll
        for (int j = 0; j < 8; ++j) pk[s][j] = 0;
      }
    }
    short* vd = vlds + (it & 1) * 5120 + p * 40 + (half << 3);
    *(s16x8*)(vd) = pk[0];
    *(s16x8*)(vd + 16) = pk[1];
    __syncthreads();
    const short* vb = vlds + (it & 1) * 5120;
    s16x8 B0 = *(const s16x8*)(vb + ((wv << 5) + ln) * 40 + (quad << 3));
    s16x8 B1 = *(const s16x8*)(vb + ((wv << 5) + 16 + ln) * 40 + (quad << 3));
#pragma unroll
    for (int mt = 0; mt < 2; ++mt) {
      s16x8 A = *(const s16x8*)(wbtA + (size_t)((it << 5) + (mt << 4) + ln) * 32 + (quad << 3));
      acc[mt][0] = __builtin_amdgcn_mfma_f32_16x16x32_bf16(A, B0, acc[mt][0], 0, 0, 0);
      acc[mt][1] = __builtin_amdgcn_mfma_f32_16x16x32_bf16(A, B1, acc[mt][1], 0, 0, 0);
    }
  }

  int hw = h << 7;
#pragma unroll
  for (int mt = 0; mt < 2; ++mt)
#pragma unroll
    for (int r = 0; r < 4; ++r) {
      int oc = (mt << 4) + (quad << 2) + r;
#pragma unroll
      for (int nt = 0; nt < 2; ++nt) {
        int px = (wv << 5) + (nt << 4) + ln;
        float val = acc[mt][nt][r];
        if (oc < 18) {
          off_out[(((size_t)b * 18 + oc) << 14) + hw + px] = val + off_b[oc];
        } else if (oc < 27) {
          float z = val + mod_b[oc - 18];
          mask_out[(((size_t)b * 9 + (oc - 18)) << 14) + hw + px] = 2.f / (1.f + expf(-z));
        }
      }
    }
}

// ---------------- kernel B: modulated deformable conv as implicit-GEMM MFMA (M=64) ----------------
// R5: geometry (bilinear weights incl mask, clamped base index + step flags) is computed ONCE
// in a prologue and stored in LDS, instead of being recomputed from dependent global loads in
// every chunk iteration. K-loop chains now start from LDS (~120cyc) and the freed registers
// let the compiler keep a full tap's 32 gathers in flight.
__global__ __launch_bounds__(256, 4) void deform_mfma_kernel(
    const float* __restrict__ x, const float* __restrict__ off,
    const float* __restrict__ mask, const unsigned short* __restrict__ wbtB,
    const float* __restrict__ bias, float* __restrict__ y) {
  __shared__ short vlds[2 * 128 * 40];          // 20480 B
  __shared__ unsigned short geow[9 * 128 * 4];  // 9216 B: w00,w01,w10,w11 bf16 (mask folded)
  __shared__ unsigned short geoi[9 * 128];      // 2304 B: i00(14b) | sx<<14 | sy<<15
  int t = threadIdx.x;
  int bx = blockIdx.x;
  int b = bx & 7, h = bx >> 3;
  int p = t & 127, half = t >> 7;
  int ln = t & 15, quad = (t >> 4) & 3, wv = t >> 6;
  int hw = h << 7;

  // ---- prologue: geometry for 128 px x 9 taps ----
  for (int i = t; i < 1152; i += 256) {
    int tap = i >> 7, p2 = i & 127;
    int ob = ((b * 18 + 2 * tap) << 14) + hw + p2;
    float dy = off[ob];
    float dx = off[ob + HW];
    float m = mask[((b * 9 + tap) << 14) + hw + p2];
    float py = dy + (float)(h + tap / 3 - 1);
    float pxf = dx + (float)(p2 + tap % 3 - 1);
    float y0f = floorf(py), x0f = floorf(pxf);
    float ly = py - y0f, lx = pxf - x0f;
    int y0 = (int)y0f, x0 = (int)x0f;
    int y1 = y0 + 1, x1 = x0 + 1;
    float fy0 = (y0 >= 0 && y0 < Hn) ? 1.f : 0.f;
    float fy1 = (y1 >= 0 && y1 < Hn) ? 1.f : 0.f;
    float fx0 = (x0 >= 0 && x0 < Wn) ? 1.f : 0.f;
    float fx1 = (x1 >= 0 && x1 < Wn) ? 1.f : 0.f;
    float w00 = (1.f - ly) * (1.f - lx) * m * fy0 * fx0;
    float w01 = (1.f - ly) * lx * m * fy0 * fx1;
    float w10 = ly * (1.f - lx) * m * fy1 * fx0;
    float w11 = ly * lx * m * fy1 * fx1;
    int cy0 = min(max(y0, 0), Hn - 1), cy1 = min(max(y1, 0), Hn - 1);
    int cx0 = min(max(x0, 0), Wn - 1), cx1 = min(max(x1, 0), Wn - 1);
    int i00 = (cy0 << 7) + cx0;
    int sx = cx1 - cx0;   // 0 or 1
    int sy = cy1 - cy0;   // 0 or 1
    unsigned short* gw = geow + i * 4;
    gw[0] = f2bf(w00);
    gw[1] = f2bf(w01);
    gw[2] = f2bf(w10);
    gw[3] = f2bf(w11);
    geoi[i] = (unsigned short)(i00 | (sx << 14) | (sy << 15));
  }
  __syncthreads();

  f32x4 acc[4][2];
#pragma unroll
  for (int mt = 0; mt < 4; ++mt)
#pragma unroll
    for (int nt = 0; nt < 2; ++nt) acc[mt][nt] = (f32x4){0.f, 0.f, 0.f, 0.f};

  const float* xb = x + ((size_t)(b << 6) << 14);

  for (int it = 0; it < 20; ++it) {
    int chunk = it / 5, tp = it - chunk * 5;
    const float* xc0 = xb + ((size_t)((chunk << 4) + (half << 3)) << 14);
    s16x8 pk[2];
#pragma unroll
    for (int s = 0; s < 2; ++s) {
      int tap = tp * 2 + s;
      if (tap < 9) {
        int gidx = (tap << 7) + p;
        u16x4 wq = *(const u16x4*)(geow + gidx * 4);
        unsigned gi = geoi[gidx];
        float w00 = bf2f(wq[0]), w01 = bf2f(wq[1]), w10 = bf2f(wq[2]), w11 = bf2f(wq[3]);
        int i00 = (int)(gi & 16383u);
        int sx = (int)((gi >> 14) & 1u);
        int i01 = i00 + sx;
        int i10 = i00 + (int)(((gi >> 15) & 1u) << 7);
        int i11 = i10 + sx;
#pragma unroll
        for (int j = 0; j < 8; ++j) {
          const float* xc = xc0 + (j << 14);
          float v = w00 * xc[i00] + w01 * xc[i01] + w10 * xc[i10] + w11 * xc[i11];
          pk[s][j] = (short)f2bf(v);
        }
      } else {
#pragma unroll
        for (int j = 0; j < 8; ++j) pk[s][j] = 0;
      }
    }
    short* vd = vlds + (it & 1) * 5120 + p * 40 + (half << 3);
    *(s16x8*)(vd) = pk[0];
    *(s16x8*)(vd + 16) = pk[1];
    __syncthreads();
    const short* vb = vlds + (it & 1) * 5120;
    s16x8 B0 = *(const s16x8*)(vb + ((wv << 5) + ln) * 40 + (quad << 3));
    s16x8 B1 = *(const s16x8*)(vb + ((wv << 5) + 16 + ln) * 40 + (quad << 3));
#pragma unroll
    for (int mt = 0; mt < 4; ++mt) {
      s16x8 A = *(const s16x8*)(wbtB + (size_t)((it << 6) + (mt << 4) + ln) * 32 + (quad << 3));
      acc[mt][0] = __builtin_amdgcn_mfma_f32_16x16x32_bf16(A, B0, acc[mt][0], 0, 0, 0);
      acc[mt][1] = __builtin_amdgcn_mfma_f32_16x16x32_bf16(A, B1, acc[mt][1], 0, 0, 0);
    }
  }

#pragma unroll
  for (int mt = 0; mt < 4; ++mt)
#pragma unroll
    for (int r = 0; r < 4; ++r) {
      int oc = (mt << 4) + (quad << 2) + r;
      float bv = bias[oc];
      float* yp = y + (((size_t)(b << 6) + oc) << 14) + hw;
      yp[(wv << 5) + ln] = acc[mt][0][r] + bv;
      yp[(wv << 5) + 16 + ln] = acc[mt][1][r] + bv;
    }
}

// ---------------- kernel C: per-channel sum/sumsq (sliced, atomics into stat) ----------------
__global__ __launch_bounds__(256) void stats2_kernel(
    const float* __restrict__ y, float* __restrict__ stat) {
  int bxx = blockIdx.x;            // 1024 = 64 ch x 16 slices
  int c = bxx & 63, sl = bxx >> 6;
  int bb = sl >> 1;
  const float4* yp = (const float4*)(y + (((size_t)bb * 64 + c) << 14) + ((sl & 1) << 13));
  float s = 0.f, ss = 0.f;
  for (int i = threadIdx.x; i < 2048; i += 256) {
    float4 v = yp[i];
    s += v.x + v.y + v.z + v.w;
    ss += v.x * v.x + v.y * v.y + v.z * v.z + v.w * v.w;
  }
#pragma unroll
  for (int o = 32; o > 0; o >>= 1) {
    s += __shfl_xor(s, o);
    ss += __shfl_xor(ss, o);
  }
  __shared__ float shs[4], shss[4];
  int lane = threadIdx.x & 63, wv = threadIdx.x >> 6;
  if (lane == 0) { shs[wv] = s; shss[wv] = ss; }
  __syncthreads();
  if (threadIdx.x == 0) {
    float S = shs[0] + shs[1] + shs[2] + shs[3];
    float SS = shss[0] + shss[1] + shss[2] + shss[3];
    atomicAdd(stat + c, S);
    atomicAdd(stat + 64 + c, SS);
  }
}

// ---------------- kernel D: batchnorm scale/shift + relu, in place ----------------
__global__ __launch_bounds__(256) void bnrelu_kernel(
    float* __restrict__ y, const float* __restrict__ stat,
    const float* __restrict__ gamma, const float* __restrict__ beta) {
  float4* y4 = (float4*)y;
  for (int i = blockIdx.x * 256 + threadIdx.x; i < 2097152; i += gridDim.x * 256) {
    int c = (i >> 12) & 63;
    float mean = stat[c] * (1.f / (float)NPIX);
    float var = stat[64 + c] * (1.f / (float)NPIX) - mean * mean;
    float r = rsqrtf(var + EPSv);
    float g = gamma[c] * r;
    float bt = beta[c] - mean * g;
    float4 v = y4[i];
    v.x = fmaxf(v.x * g + bt, 0.f);
    v.y = fmaxf(v.y * g + bt, 0.f);
    v.z = fmaxf(v.z * g + bt, 0.f);
    v.w = fmaxf(v.w * g + bt, 0.f);
    y4[i] = v;
  }
}

extern "C" void kernel_launch(void* const* d_in, const int* in_sizes, int n_in,
                              void* d_out, int out_size, void* d_ws, size_t ws_size,
                              hipStream_t stream) {
  const float* x     = (const float*)d_in[0];
  const float* off_w = (const float*)d_in[1];
  const float* off_b = (const float*)d_in[2];
  const float* mod_w = (const float*)d_in[3];
  const float* mod_b = (const float*)d_in[4];
  const float* w     = (const float*)d_in[5];
  const float* b     = (const float*)d_in[6];
  const float* gamma = (const float*)d_in[7];
  const float* beta  = (const float*)d_in[8];
  float* out = (float*)d_out;
  float* ws  = (float*)d_ws;

  float* offo  = ws + OFF_OFF;
  float* masko = ws + MASK_OFF;
  unsigned short* wbtA = (unsigned short*)(ws + WBTA_OFF);
  unsigned short* wbtB = (unsigned short*)(ws + WBTB_OFF);
  float* stat  = ws + STAT_OFF;

  prep_kernel<<<240, 256, 0, stream>>>(off_w, mod_w, w, wbtA, wbtB, stat);
  convA_mfma_kernel<<<1024, 256, 0, stream>>>(x, wbtA, off_b, mod_b, offo, masko);
  deform_mfma_kernel<<<1024, 256, 0, stream>>>(x, offo, masko, wbtB, b, out);
  stats2_kernel<<<1024, 256, 0, stream>>>(out, stat);
  bnrelu_kernel<<<8192, 256, 0, stream>>>(out, stat, gamma, beta);
}

// Round 6
// 297.571 us; speedup vs baseline: 1.9121x; 1.1157x over previous
//
#include <hip/hip_runtime.h>
#include <math.h>

// Problem constants: B=8, C=64 (in), OC=64 (out), H=W=128, K=3x3=9, PAD=1.
#define Hn 128
#define Wn 128
#define HW 16384
#define NPIX 131072
#define EPSv 1e-5f

// ws layout (floats)
#define OFF_OFF  0            // 8*18*16384 = 2359296
#define MASK_OFF 2359296      // 8*9*16384  = 1179648
#define WBTA_OFF 3538944      // 20480 shorts (convA weights, [it(20)][oc(32)][e(32)]) = 10240 floats
#define WBTB_OFF 3549184      // 40960 shorts (deform weights, [it(20)][oc(64)][e(32)]) = 20480 floats
#define STAT_OFF 3569664      // 128 (sum[64], sumsq[64])

// K-packing: 640 = 4 c16-chunks x 5 tap-pairs x 32. K-elem e in [0,32):
//   tap = tp*2 + (e>>4)  (tap 9 = zero pad), c = chunk*16 + (e&15).
// it = chunk*5 + tp, chunk OUTER (x L1 reuse across taps), tp inner.

typedef short s16x8 __attribute__((ext_vector_type(8)));
typedef unsigned short u16x4 __attribute__((ext_vector_type(4)));
typedef float f32x4 __attribute__((ext_vector_type(4)));
// 8B vector load with only 4B alignment guarantee (gfx9+ HW handles unaligned global)
typedef float f32x2u __attribute__((ext_vector_type(2))) __attribute__((aligned(4)));

__device__ __forceinline__ unsigned short f2bf(float f) {
  unsigned u = __float_as_uint(f);
  return (unsigned short)((u + 0x7fffu + ((u >> 16) & 1u)) >> 16);  // RNE
}
__device__ __forceinline__ float bf2f(unsigned short s) {
  return __uint_as_float((unsigned)s << 16);
}

// ---------------- prep: pack weights into MFMA A-operand order; zero stat ----------------
__global__ __launch_bounds__(256) void prep_kernel(
    const float* __restrict__ off_w, const float* __restrict__ mod_w,
    const float* __restrict__ w, unsigned short* __restrict__ wbtA,
    unsigned short* __restrict__ wbtB, float* __restrict__ stat) {
  int i = blockIdx.x * 256 + threadIdx.x;
  if (i < 128) stat[i] = 0.f;
  if (i < 20480) {
    int e = i & 31, oc = (i >> 5) & 31, it = i >> 10;
    int tp = it % 5, chunk = it / 5;
    int tap = tp * 2 + (e >> 4);
    int c = (chunk << 4) + (e & 15);
    float v = 0.f;
    if (tap < 9) {
      if (oc < 18) v = off_w[(oc * 64 + c) * 9 + tap];
      else if (oc < 27) v = mod_w[((oc - 18) * 64 + c) * 9 + tap];
    }
    wbtA[i] = f2bf(v);
  } else if (i < 20480 + 40960) {
    int j = i - 20480;
    int e = j & 31, oc = (j >> 5) & 63, it = j >> 11;
    int tp = it % 5, chunk = it / 5;
    int tap = tp * 2 + (e >> 4);
    int c = (chunk << 4) + (e & 15);
    float v = (tap < 9) ? w[(oc * 64 + c) * 9 + tap] : 0.f;
    wbtB[j] = f2bf(v);
  }
}

// ---------------- kernel A: offset+mask conv as implicit-GEMM MFMA (M=32 incl pad) ----------------
__global__ __launch_bounds__(256, 4) void convA_mfma_kernel(
    const float* __restrict__ x, const unsigned short* __restrict__ wbtA,
    const float* __restrict__ off_b, const float* __restrict__ mod_b,
    float* __restrict__ off_out, float* __restrict__ mask_out) {
  __shared__ short vlds[2 * 128 * 40];
  int t = threadIdx.x;
  int bx = blockIdx.x;
  int b = bx & 7, h = bx >> 3;
  int p = t & 127, half = t >> 7;
  int ln = t & 15, quad = (t >> 4) & 3, wv = t >> 6;

  f32x4 acc[2][2];
#pragma unroll
  for (int mt = 0; mt < 2; ++mt)
#pragma unroll
    for (int nt = 0; nt < 2; ++nt) acc[mt][nt] = (f32x4){0.f, 0.f, 0.f, 0.f};

  const float* xb = x + ((size_t)(b << 6) << 14);

  for (int it = 0; it < 20; ++it) {
    int chunk = it / 5, tp = it - chunk * 5;
    const float* xc0 = xb + ((size_t)((chunk << 4) + (half << 3)) << 14);
    // batched loads: both taps' 8 channels issued before any math
    float av[2][8];
#pragma unroll
    for (int s = 0; s < 2; ++s) {
      int tap = tp * 2 + s;
      if (tap < 9) {
        int gy = h + tap / 3 - 1;
        int gx = p + tap % 3 - 1;
        bool ok = (gy >= 0) && (gy < Hn) && (gx >= 0) && (gx < Wn);
        int idx = ok ? ((gy << 7) + gx) : 0;
#pragma unroll
        for (int j = 0; j < 8; ++j) av[s][j] = ok ? xc0[(j << 14) + idx] : 0.f;
      } else {
#pragma unroll
        for (int j = 0; j < 8; ++j) av[s][j] = 0.f;
      }
    }
    s16x8 pk[2];
#pragma unroll
    for (int s = 0; s < 2; ++s)
#pragma unroll
      for (int j = 0; j < 8; ++j) pk[s][j] = (short)f2bf(av[s][j]);

    short* vd = vlds + (it & 1) * 5120 + p * 40 + (half << 3);
    *(s16x8*)(vd) = pk[0];
    *(s16x8*)(vd + 16) = pk[1];
    __syncthreads();
    const short* vb = vlds + (it & 1) * 5120;
    s16x8 B0 = *(const s16x8*)(vb + ((wv << 5) + ln) * 40 + (quad << 3));
    s16x8 B1 = *(const s16x8*)(vb + ((wv << 5) + 16 + ln) * 40 + (quad << 3));
#pragma unroll
    for (int mt = 0; mt < 2; ++mt) {
      s16x8 A = *(const s16x8*)(wbtA + (size_t)((it << 5) + (mt << 4) + ln) * 32 + (quad << 3));
      acc[mt][0] = __builtin_amdgcn_mfma_f32_16x16x32_bf16(A, B0, acc[mt][0], 0, 0, 0);
      acc[mt][1] = __builtin_amdgcn_mfma_f32_16x16x32_bf16(A, B1, acc[mt][1], 0, 0, 0);
    }
  }

  int hw = h << 7;
#pragma unroll
  for (int mt = 0; mt < 2; ++mt)
#pragma unroll
    for (int r = 0; r < 4; ++r) {
      int oc = (mt << 4) + (quad << 2) + r;
#pragma unroll
      for (int nt = 0; nt < 2; ++nt) {
        int px = (wv << 5) + (nt << 4) + ln;
        float val = acc[mt][nt][r];
        if (oc < 18) {
          off_out[(((size_t)b * 18 + oc) << 14) + hw + px] = val + off_b[oc];
        } else if (oc < 27) {
          float z = val + mod_b[oc - 18];
          mask_out[(((size_t)b * 9 + (oc - 18)) << 14) + hw + px] = 2.f / (1.f + expf(-z));
        }
      }
    }
}

// ---------------- kernel B: modulated deformable conv as implicit-GEMM MFMA (M=64) ----------------
// R6: separable layout-space bilinear weights -> 2 paired (float2) gathers per (tap,channel)
// instead of 4 scalar gathers. Geometry per (tap,px): gy0,gy1 (rows rbase,rbase+1; mask folded),
// gx0,gx1 (cols cbase,cbase+1), ibase = rbase*128+cbase with rbase,cbase <= 126 so ibase+129
// stays inside the channel plane. Clamped/border corners are remapped so out-of-window slots
// carry weight 0 (verified for x0 in {-1,127,128}).
__global__ __launch_bounds__(256, 3) void deform_mfma_kernel(
    const float* __restrict__ x, const float* __restrict__ off,
    const float* __restrict__ mask, const unsigned short* __restrict__ wbtB,
    const float* __restrict__ bias, float* __restrict__ y) {
  __shared__ short vlds[2 * 128 * 40];          // 20480 B
  __shared__ unsigned short geow[9 * 128 * 4];  // 9216 B: gy0,gy1,gx0,gx1 bf16
  __shared__ unsigned short geoi[9 * 128];      // 2304 B: ibase (14b)
  int t = threadIdx.x;
  int bx = blockIdx.x;
  int b = bx & 7, h = bx >> 3;
  int p = t & 127, half = t >> 7;
  int ln = t & 15, quad = (t >> 4) & 3, wv = t >> 6;
  int hw = h << 7;

  // ---- prologue: geometry for 128 px x 9 taps ----
  for (int i = t; i < 1152; i += 256) {
    int tap = i >> 7, p2 = i & 127;
    int ob = ((b * 18 + 2 * tap) << 14) + hw + p2;
    float dy = off[ob];
    float dx = off[ob + HW];
    float m = mask[((b * 9 + tap) << 14) + hw + p2];
    float py = dy + (float)(h + tap / 3 - 1);
    float pxf = dx + (float)(p2 + tap % 3 - 1);
    float y0f = floorf(py), x0f = floorf(pxf);
    float ly = py - y0f, lx = pxf - x0f;
    int y0 = (int)y0f, x0 = (int)x0f;
    int y1 = y0 + 1, x1 = x0 + 1;
    float fy0 = (y0 >= 0 && y0 < Hn) ? 1.f : 0.f;
    float fy1 = (y1 >= 0 && y1 < Hn) ? 1.f : 0.f;
    float fx0 = (x0 >= 0 && x0 < Wn) ? 1.f : 0.f;
    float fx1 = (x1 >= 0 && x1 < Wn) ? 1.f : 0.f;
    // axis weights targeting clamped coords
    float ax0 = (1.f - lx) * fx0, ax1 = lx * fx1;          // -> cols cx0, cx1
    float ay0 = (1.f - ly) * fy0 * m, ay1 = ly * fy1 * m;  // -> rows cy0, cy1 (mask folded)
    int cy0 = min(max(y0, 0), Hn - 1), cy1 = min(max(y1, 0), Hn - 1);
    int cx0 = min(max(x0, 0), Wn - 1), cx1 = min(max(x1, 0), Wn - 1);
    int cbase = min(cx0, Wn - 2), rbase = min(cy0, Hn - 2);
    // remap into layout slots {base, base+1}
    float gx0 = (cx0 == cbase ? ax0 : 0.f) + (cx1 == cbase ? ax1 : 0.f);
    float gx1 = (cx0 == cbase + 1 ? ax0 : 0.f) + (cx1 == cbase + 1 ? ax1 : 0.f);
    float gy0 = (cy0 == rbase ? ay0 : 0.f) + (cy1 == rbase ? ay1 : 0.f);
    float gy1 = (cy0 == rbase + 1 ? ay0 : 0.f) + (cy1 == rbase + 1 ? ay1 : 0.f);
    unsigned short* gw = geow + i * 4;
    gw[0] = f2bf(gy0);
    gw[1] = f2bf(gy1);
    gw[2] = f2bf(gx0);
    gw[3] = f2bf(gx1);
    geoi[i] = (unsigned short)((rbase << 7) + cbase);
  }
  __syncthreads();

  f32x4 acc[4][2];
#pragma unroll
  for (int mt = 0; mt < 4; ++mt)
#pragma unroll
    for (int nt = 0; nt < 2; ++nt) acc[mt][nt] = (f32x4){0.f, 0.f, 0.f, 0.f};

  const float* xb = x + ((size_t)(b << 6) << 14);

  for (int it = 0; it < 20; ++it) {
    int chunk = it / 5, tp = it - chunk * 5;
    const float* xc0 = xb + ((size_t)((chunk << 4) + (half << 3)) << 14);
    // geometry for both taps
    float gy0[2], gy1[2], gx0[2], gx1[2];
    const float* xp[2];
#pragma unroll
    for (int s = 0; s < 2; ++s) {
      int tap = tp * 2 + s;
      if (tap < 9) {
        int gidx = (tap << 7) + p;
        u16x4 wq = *(const u16x4*)(geow + gidx * 4);
        unsigned ib = geoi[gidx];
        gy0[s] = bf2f(wq[0]);
        gy1[s] = bf2f(wq[1]);
        gx0[s] = bf2f(wq[2]);
        gx1[s] = bf2f(wq[3]);
        xp[s] = xc0 + ib;
      } else {
        xp[s] = xc0;  // dead
        gy0[s] = gy1[s] = gx0[s] = gx1[s] = 0.f;
      }
    }
    // batched paired gathers: 2 rows x 8 channels x 2 taps
    f32x2u r0[2][8], r1[2][8];
#pragma unroll
    for (int s = 0; s < 2; ++s) {
      int tap = tp * 2 + s;
      if (tap < 9) {
#pragma unroll
        for (int j = 0; j < 8; ++j) {
          r0[s][j] = *(const f32x2u*)(xp[s] + (j << 14));
          r1[s][j] = *(const f32x2u*)(xp[s] + (j << 14) + Wn);
        }
      }
    }
    s16x8 pk[2];
#pragma unroll
    for (int s = 0; s < 2; ++s) {
      int tap = tp * 2 + s;
      if (tap < 9) {
#pragma unroll
        for (int j = 0; j < 8; ++j) {
          float v = gy0[s] * (gx0[s] * r0[s][j][0] + gx1[s] * r0[s][j][1]) +
                    gy1[s] * (gx0[s] * r1[s][j][0] + gx1[s] * r1[s][j][1]);
          pk[s][j] = (short)f2bf(v);
        }
      } else {
#pragma unroll
        for (int j = 0; j < 8; ++j) pk[s][j] = 0;
      }
    }
    short* vd = vlds + (it & 1) * 5120 + p * 40 + (half << 3);
    *(s16x8*)(vd) = pk[0];
    *(s16x8*)(vd + 16) = pk[1];
    __syncthreads();
    const short* vb = vlds + (it & 1) * 5120;
    s16x8 B0 = *(const s16x8*)(vb + ((wv << 5) + ln) * 40 + (quad << 3));
    s16x8 B1 = *(const s16x8*)(vb + ((wv << 5) + 16 + ln) * 40 + (quad << 3));
#pragma unroll
    for (int mt = 0; mt < 4; ++mt) {
      s16x8 A = *(const s16x8*)(wbtB + (size_t)((it << 6) + (mt << 4) + ln) * 32 + (quad << 3));
      acc[mt][0] = __builtin_amdgcn_mfma_f32_16x16x32_bf16(A, B0, acc[mt][0], 0, 0, 0);
      acc[mt][1] = __builtin_amdgcn_mfma_f32_16x16x32_bf16(A, B1, acc[mt][1], 0, 0, 0);
    }
  }

#pragma unroll
  for (int mt = 0; mt < 4; ++mt)
#pragma unroll
    for (int r = 0; r < 4; ++r) {
      int oc = (mt << 4) + (quad << 2) + r;
      float bv = bias[oc];
      float* yp = y + (((size_t)(b << 6) + oc) << 14) + hw;
      yp[(wv << 5) + ln] = acc[mt][0][r] + bv;
      yp[(wv << 5) + 16 + ln] = acc[mt][1][r] + bv;
    }
}

// ---------------- kernel C: per-channel sum/sumsq (sliced, atomics into stat) ----------------
__global__ __launch_bounds__(256) void stats2_kernel(
    const float* __restrict__ y, float* __restrict__ stat) {
  int bxx = blockIdx.x;            // 1024 = 64 ch x 16 slices
  int c = bxx & 63, sl = bxx >> 6;
  int bb = sl >> 1;
  const float4* yp = (const float4*)(y + (((size_t)bb * 64 + c) << 14) + ((sl & 1) << 13));
  float s = 0.f, ss = 0.f;
  for (int i = threadIdx.x; i < 2048; i += 256) {
    float4 v = yp[i];
    s += v.x + v.y + v.z + v.w;
    ss += v.x * v.x + v.y * v.y + v.z * v.z + v.w * v.w;
  }
#pragma unroll
  for (int o = 32; o > 0; o >>= 1) {
    s += __shfl_xor(s, o);
    ss += __shfl_xor(ss, o);
  }
  __shared__ float shs[4], shss[4];
  int lane = threadIdx.x & 63, wv = threadIdx.x >> 6;
  if (lane == 0) { shs[wv] = s; shss[wv] = ss; }
  __syncthreads();
  if (threadIdx.x == 0) {
    float S = shs[0] + shs[1] + shs[2] + shs[3];
    float SS = shss[0] + shss[1] + shss[2] + shss[3];
    atomicAdd(stat + c, S);
    atomicAdd(stat + 64 + c, SS);
  }
}

// ---------------- kernel D: batchnorm scale/shift + relu, in place ----------------
__global__ __launch_bounds__(256) void bnrelu_kernel(
    float* __restrict__ y, const float* __restrict__ stat,
    const float* __restrict__ gamma, const float* __restrict__ beta) {
  float4* y4 = (float4*)y;
  for (int i = blockIdx.x * 256 + threadIdx.x; i < 2097152; i += gridDim.x * 256) {
    int c = (i >> 12) & 63;
    float mean = stat[c] * (1.f / (float)NPIX);
    float var = stat[64 + c] * (1.f / (float)NPIX) - mean * mean;
    float r = rsqrtf(var + EPSv);
    float g = gamma[c] * r;
    float bt = beta[c] - mean * g;
    float4 v = y4[i];
    v.x = fmaxf(v.x * g + bt, 0.f);
    v.y = fmaxf(v.y * g + bt, 0.f);
    v.z = fmaxf(v.z * g + bt, 0.f);
    v.w = fmaxf(v.w * g + bt, 0.f);
    y4[i] = v;
  }
}

extern "C" void kernel_launch(void* const* d_in, const int* in_sizes, int n_in,
                              void* d_out, int out_size, void* d_ws, size_t ws_size,
                              hipStream_t stream) {
  const float* x     = (const float*)d_in[0];
  const float* off_w = (const float*)d_in[1];
  const float* off_b = (const float*)d_in[2];
  const float* mod_w = (const float*)d_in[3];
  const float* mod_b = (const float*)d_in[4];
  const float* w     = (const float*)d_in[5];
  const float* b     = (const float*)d_in[6];
  const float* gamma = (const float*)d_in[7];
  const float* beta  = (const float*)d_in[8];
  float* out = (float*)d_out;
  float* ws  = (float*)d_ws;

  float* offo  = ws + OFF_OFF;
  float* masko = ws + MASK_OFF;
  unsigned short* wbtA = (unsigned short*)(ws + WBTA_OFF);
  unsigned short* wbtB = (unsigned short*)(ws + WBTB_OFF);
  float* stat  = ws + STAT_OFF;

  prep_kernel<<<240, 256, 0, stream>>>(off_w, mod_w, w, wbtA, wbtB, stat);
  convA_mfma_kernel<<<1024, 256, 0, stream>>>(x, wbtA, off_b, mod_b, offo, masko);
  deform_mfma_kernel<<<1024, 256, 0, stream>>>(x, offo, masko, wbtB, b, out);
  stats2_kernel<<<1024, 256, 0, stream>>>(out, stat);
  bnrelu_kernel<<<8192, 256, 0, stream>>>(out, stat, gamma, beta);
}

// Round 8
// 297.435 us; speedup vs baseline: 1.9130x; 1.0005x over previous
//
#include <hip/hip_runtime.h>
#include <math.h>

// Problem constants: B=8, C=64 (in), OC=64 (out), H=W=128, K=3x3=9, PAD=1.
#define Hn 128
#define Wn 128
#define HW 16384
#define NPIX 131072
#define EPSv 1e-5f

// ws layout (floats)
#define OFF_OFF  0            // 8*18*16384 = 2359296
#define MASK_OFF 2359296      // 8*9*16384  = 1179648
#define WBTA_OFF 3538944      // 20480 shorts (convA weights, [it(20)][oc(32)][e(32)]) = 10240 floats
#define WBTB_OFF 3549184      // 40960 shorts (deform weights, [it(20)][oc(64)][e(32)]) = 20480 floats
#define STAT_OFF 3569664      // 128 (sum[64], sumsq[64])

// K-packing: 640 = 4 c16-chunks x 5 tap-pairs x 32. K-elem e in [0,32):
//   tap = tp*2 + (e>>4)  (tap 9 = zero pad), c = chunk*16 + (e&15).
// it = chunk*5 + tp, chunk OUTER (x L1 reuse across taps), tp inner.
// R8 bisect: convA = R7 barrier-free direct-fragment; deform = R6 LDS-staged (known good).

typedef short s16x8 __attribute__((ext_vector_type(8)));
typedef unsigned short u16x4 __attribute__((ext_vector_type(4)));
typedef float f32x4 __attribute__((ext_vector_type(4)));
// 8B vector load with only 4B alignment guarantee (gfx9+ HW handles unaligned global)
typedef float f32x2u __attribute__((ext_vector_type(2))) __attribute__((aligned(4)));

__device__ __forceinline__ unsigned short f2bf(float f) {
  unsigned u = __float_as_uint(f);
  return (unsigned short)((u + 0x7fffu + ((u >> 16) & 1u)) >> 16);  // RNE
}
__device__ __forceinline__ float bf2f(unsigned short s) {
  return __uint_as_float((unsigned)s << 16);
}

// ---------------- prep: pack weights into MFMA A-operand order; zero stat ----------------
__global__ __launch_bounds__(256) void prep_kernel(
    const float* __restrict__ off_w, const float* __restrict__ mod_w,
    const float* __restrict__ w, unsigned short* __restrict__ wbtA,
    unsigned short* __restrict__ wbtB, float* __restrict__ stat) {
  int i = blockIdx.x * 256 + threadIdx.x;
  if (i < 128) stat[i] = 0.f;
  if (i < 20480) {
    int e = i & 31, oc = (i >> 5) & 31, it = i >> 10;
    int tp = it % 5, chunk = it / 5;
    int tap = tp * 2 + (e >> 4);
    int c = (chunk << 4) + (e & 15);
    float v = 0.f;
    if (tap < 9) {
      if (oc < 18) v = off_w[(oc * 64 + c) * 9 + tap];
      else if (oc < 27) v = mod_w[((oc - 18) * 64 + c) * 9 + tap];
    }
    wbtA[i] = f2bf(v);
  } else if (i < 20480 + 40960) {
    int j = i - 20480;
    int e = j & 31, oc = (j >> 5) & 63, it = j >> 11;
    int tp = it % 5, chunk = it / 5;
    int tap = tp * 2 + (e >> 4);
    int c = (chunk << 4) + (e & 15);
    float v = (tap < 9) ? w[(oc * 64 + c) * 9 + tap] : 0.f;
    wbtB[j] = f2bf(v);
  }
}

// ---------------- kernel A: offset+mask conv, barrier-free direct-fragment MFMA (R7) ----------------
__global__ __launch_bounds__(256, 4) void convA_mfma_kernel(
    const float* __restrict__ x, const unsigned short* __restrict__ wbtA,
    const float* __restrict__ off_b, const float* __restrict__ mod_b,
    float* __restrict__ off_out, float* __restrict__ mask_out) {
  int t = threadIdx.x;
  int bx = blockIdx.x;
  int b = bx & 7, h = bx >> 3;
  int ln = t & 15, quad = (t >> 4) & 3, wv = t >> 6;
  int p0 = (wv << 5) + ln, p1 = p0 + 16;
  int s_ = quad >> 1, cj = (quad & 1) << 3;

  f32x4 acc[2][2];
#pragma unroll
  for (int mt = 0; mt < 2; ++mt)
#pragma unroll
    for (int nt = 0; nt < 2; ++nt) acc[mt][nt] = (f32x4){0.f, 0.f, 0.f, 0.f};

  const float* xb = x + ((size_t)(b << 6) << 14);

  for (int it = 0; it < 20; ++it) {
    int chunk = it / 5, tp = it - chunk * 5;
    int tap = tp * 2 + s_;
    s16x8 B0 = (s16x8){0, 0, 0, 0, 0, 0, 0, 0};
    s16x8 B1 = (s16x8){0, 0, 0, 0, 0, 0, 0, 0};
    if (tap < 9) {
      const float* xc0 = xb + ((size_t)((chunk << 4) + cj) << 14);
      int gy = h + tap / 3 - 1;
      bool oky = (gy >= 0) && (gy < Hn);
      int gx0 = p0 + tap % 3 - 1;
      int gx1 = p1 + tap % 3 - 1;
      bool ok0 = oky && (gx0 >= 0) && (gx0 < Wn);
      bool ok1 = oky && (gx1 >= 0) && (gx1 < Wn);
      int i0 = ok0 ? ((gy << 7) + gx0) : 0;
      int i1 = ok1 ? ((gy << 7) + gx1) : 0;
      float a0[8], a1[8];
#pragma unroll
      for (int j = 0; j < 8; ++j) {
        a0[j] = ok0 ? xc0[(j << 14) + i0] : 0.f;
        a1[j] = ok1 ? xc0[(j << 14) + i1] : 0.f;
      }
#pragma unroll
      for (int j = 0; j < 8; ++j) {
        B0[j] = (short)f2bf(a0[j]);
        B1[j] = (short)f2bf(a1[j]);
      }
    }
#pragma unroll
    for (int mt = 0; mt < 2; ++mt) {
      s16x8 A = *(const s16x8*)(wbtA + (size_t)((it << 5) + (mt << 4) + ln) * 32 + (quad << 3));
      acc[mt][0] = __builtin_amdgcn_mfma_f32_16x16x32_bf16(A, B0, acc[mt][0], 0, 0, 0);
      acc[mt][1] = __builtin_amdgcn_mfma_f32_16x16x32_bf16(A, B1, acc[mt][1], 0, 0, 0);
    }
  }

  int hw = h << 7;
#pragma unroll
  for (int mt = 0; mt < 2; ++mt)
#pragma unroll
    for (int r = 0; r < 4; ++r) {
      int oc = (mt << 4) + (quad << 2) + r;
#pragma unroll
      for (int nt = 0; nt < 2; ++nt) {
        int px = (wv << 5) + (nt << 4) + ln;
        float val = acc[mt][nt][r];
        if (oc < 18) {
          off_out[(((size_t)b * 18 + oc) << 14) + hw + px] = val + off_b[oc];
        } else if (oc < 27) {
          float z = val + mod_b[oc - 18];
          mask_out[(((size_t)b * 9 + (oc - 18)) << 14) + hw + px] = 2.f / (1.f + expf(-z));
        }
      }
    }
}

// ---------------- kernel B: modulated deformable conv, R6 LDS-staged (known good) ----------------
__global__ __launch_bounds__(256, 3) void deform_mfma_kernel(
    const float* __restrict__ x, const float* __restrict__ off,
    const float* __restrict__ mask, const unsigned short* __restrict__ wbtB,
    const float* __restrict__ bias, float* __restrict__ y) {
  __shared__ short vlds[2 * 128 * 40];          // 20480 B
  __shared__ unsigned short geow[9 * 128 * 4];  // 9216 B: gy0,gy1,gx0,gx1 bf16
  __shared__ unsigned short geoi[9 * 128];      // 2304 B: ibase (14b)
  int t = threadIdx.x;
  int bx = blockIdx.x;
  int b = bx & 7, h = bx >> 3;
  int p = t & 127, half = t >> 7;
  int ln = t & 15, quad = (t >> 4) & 3, wv = t >> 6;
  int hw = h << 7;

  // ---- prologue: geometry for 128 px x 9 taps ----
  for (int i = t; i < 1152; i += 256) {
    int tap = i >> 7, p2 = i & 127;
    int ob = ((b * 18 + 2 * tap) << 14) + hw + p2;
    float dy = off[ob];
    float dx = off[ob + HW];
    float m = mask[((b * 9 + tap) << 14) + hw + p2];
    float py = dy + (float)(h + tap / 3 - 1);
    float pxf = dx + (float)(p2 + tap % 3 - 1);
    float y0f = floorf(py), x0f = floorf(pxf);
    float ly = py - y0f, lx = pxf - x0f;
    int y0 = (int)y0f, x0 = (int)x0f;
    int y1 = y0 + 1, x1 = x0 + 1;
    float fy0 = (y0 >= 0 && y0 < Hn) ? 1.f : 0.f;
    float fy1 = (y1 >= 0 && y1 < Hn) ? 1.f : 0.f;
    float fx0 = (x0 >= 0 && x0 < Wn) ? 1.f : 0.f;
    float fx1 = (x1 >= 0 && x1 < Wn) ? 1.f : 0.f;
    float ax0 = (1.f - lx) * fx0, ax1 = lx * fx1;          // -> cols cx0, cx1
    float ay0 = (1.f - ly) * fy0 * m, ay1 = ly * fy1 * m;  // -> rows cy0, cy1 (mask folded)
    int cy0 = min(max(y0, 0), Hn - 1), cy1 = min(max(y1, 0), Hn - 1);
    int cx0 = min(max(x0, 0), Wn - 1), cx1 = min(max(x1, 0), Wn - 1);
    int cbase = min(cx0, Wn - 2), rbase = min(cy0, Hn - 2);
    float gx0 = (cx0 == cbase ? ax0 : 0.f) + (cx1 == cbase ? ax1 : 0.f);
    float gx1 = (cx0 == cbase + 1 ? ax0 : 0.f) + (cx1 == cbase + 1 ? ax1 : 0.f);
    float gy0 = (cy0 == rbase ? ay0 : 0.f) + (cy1 == rbase ? ay1 : 0.f);
    float gy1 = (cy0 == rbase + 1 ? ay0 : 0.f) + (cy1 == rbase + 1 ? ay1 : 0.f);
    unsigned short* gw = geow + i * 4;
    gw[0] = f2bf(gy0);
    gw[1] = f2bf(gy1);
    gw[2] = f2bf(gx0);
    gw[3] = f2bf(gx1);
    geoi[i] = (unsigned short)((rbase << 7) + cbase);
  }
  __syncthreads();

  f32x4 acc[4][2];
#pragma unroll
  for (int mt = 0; mt < 4; ++mt)
#pragma unroll
    for (int nt = 0; nt < 2; ++nt) acc[mt][nt] = (f32x4){0.f, 0.f, 0.f, 0.f};

  const float* xb = x + ((size_t)(b << 6) << 14);

  for (int it = 0; it < 20; ++it) {
    int chunk = it / 5, tp = it - chunk * 5;
    const float* xc0 = xb + ((size_t)((chunk << 4) + (half << 3)) << 14);
    // geometry for both taps
    float gy0[2], gy1[2], gx0[2], gx1[2];
    const float* xp[2];
#pragma unroll
    for (int s = 0; s < 2; ++s) {
      int tap = tp * 2 + s;
      if (tap < 9) {
        int gidx = (tap << 7) + p;
        u16x4 wq = *(const u16x4*)(geow + gidx * 4);
        unsigned ib = geoi[gidx];
        gy0[s] = bf2f(wq[0]);
        gy1[s] = bf2f(wq[1]);
        gx0[s] = bf2f(wq[2]);
        gx1[s] = bf2f(wq[3]);
        xp[s] = xc0 + ib;
      } else {
        xp[s] = xc0;  // dead
        gy0[s] = gy1[s] = gx0[s] = gx1[s] = 0.f;
      }
    }
    // batched paired gathers: 2 rows x 8 channels x 2 taps
    f32x2u r0[2][8], r1[2][8];
#pragma unroll
    for (int s = 0; s < 2; ++s) {
      int tap = tp * 2 + s;
      if (tap < 9) {
#pragma unroll
        for (int j = 0; j < 8; ++j) {
          r0[s][j] = *(const f32x2u*)(xp[s] + (j << 14));
          r1[s][j] = *(const f32x2u*)(xp[s] + (j << 14) + Wn);
        }
      }
    }
    s16x8 pk[2];
#pragma unroll
    for (int s = 0; s < 2; ++s) {
      int tap = tp * 2 + s;
      if (tap < 9) {
#pragma unroll
        for (int j = 0; j < 8; ++j) {
          float v = gy0[s] * (gx0[s] * r0[s][j][0] + gx1[s] * r0[s][j][1]) +
                    gy1[s] * (gx0[s] * r1[s][j][0] + gx1[s] * r1[s][j][1]);
          pk[s][j] = (short)f2bf(v);
        }
      } else {
#pragma unroll
        for (int j = 0; j < 8; ++j) pk[s][j] = 0;
      }
    }
    short* vd = vlds + (it & 1) * 5120 + p * 40 + (half << 3);
    *(s16x8*)(vd) = pk[0];
    *(s16x8*)(vd + 16) = pk[1];
    __syncthreads();
    const short* vb = vlds + (it & 1) * 5120;
    s16x8 B0 = *(const s16x8*)(vb + ((wv << 5) + ln) * 40 + (quad << 3));
    s16x8 B1 = *(const s16x8*)(vb + ((wv << 5) + 16 + ln) * 40 + (quad << 3));
#pragma unroll
    for (int mt = 0; mt < 4; ++mt) {
      s16x8 A = *(const s16x8*)(wbtB + (size_t)((it << 6) + (mt << 4) + ln) * 32 + (quad << 3));
      acc[mt][0] = __builtin_amdgcn_mfma_f32_16x16x32_bf16(A, B0, acc[mt][0], 0, 0, 0);
      acc[mt][1] = __builtin_amdgcn_mfma_f32_16x16x32_bf16(A, B1, acc[mt][1], 0, 0, 0);
    }
  }

#pragma unroll
  for (int mt = 0; mt < 4; ++mt)
#pragma unroll
    for (int r = 0; r < 4; ++r) {
      int oc = (mt << 4) + (quad << 2) + r;
      float bv = bias[oc];
      float* yp = y + (((size_t)(b << 6) + oc) << 14) + hw;
      yp[(wv << 5) + ln] = acc[mt][0][r] + bv;
      yp[(wv << 5) + 16 + ln] = acc[mt][1][r] + bv;
    }
}

// ---------------- kernel C: per-channel sum/sumsq (sliced, atomics into stat) ----------------
__global__ __launch_bounds__(256) void stats2_kernel(
    const float* __restrict__ y, float* __restrict__ stat) {
  int bxx = blockIdx.x;            // 1024 = 64 ch x 16 slices
  int c = bxx & 63, sl = bxx >> 6;
  int bb = sl >> 1;
  const float4* yp = (const float4*)(y + (((size_t)bb * 64 + c) << 14) + ((sl & 1) << 13));
  float s = 0.f, ss = 0.f;
  for (int i = threadIdx.x; i < 2048; i += 256) {
    float4 v = yp[i];
    s += v.x + v.y + v.z + v.w;
    ss += v.x * v.x + v.y * v.y + v.z * v.z + v.w * v.w;
  }
#pragma unroll
  for (int o = 32; o > 0; o >>= 1) {
    s += __shfl_xor(s, o);
    ss += __shfl_xor(ss, o);
  }
  __shared__ float shs[4], shss[4];
  int lane = threadIdx.x & 63, wv = threadIdx.x >> 6;
  if (lane == 0) { shs[wv] = s; shss[wv] = ss; }
  __syncthreads();
  if (threadIdx.x == 0) {
    float S = shs[0] + shs[1] + shs[2] + shs[3];
    float SS = shss[0] + shss[1] + shss[2] + shss[3];
    atomicAdd(stat + c, S);
    atomicAdd(stat + 64 + c, SS);
  }
}

// ---------------- kernel D: batchnorm scale/shift + relu, in place ----------------
__global__ __launch_bounds__(256) void bnrelu_kernel(
    float* __restrict__ y, const float* __restrict__ stat,
    const float* __restrict__ gamma, const float* __restrict__ beta) {
  float4* y4 = (float4*)y;
  for (int i = blockIdx.x * 256 + threadIdx.x; i < 2097152; i += gridDim.x * 256) {
    int c = (i >> 12) & 63;
    float mean = stat[c] * (1.f / (float)NPIX);
    float var = stat[64 + c] * (1.f / (float)NPIX) - mean * mean;
    float r = rsqrtf(var + EPSv);
    float g = gamma[c] * r;
    float bt = beta[c] - mean * g;
    float4 v = y4[i];
    v.x = fmaxf(v.x * g + bt, 0.f);
    v.y = fmaxf(v.y * g + bt, 0.f);
    v.z = fmaxf(v.z * g + bt, 0.f);
    v.w = fmaxf(v.w * g + bt, 0.f);
    y4[i] = v;
  }
}

extern "C" void kernel_launch(void* const* d_in, const int* in_sizes, int n_in,
                              void* d_out, int out_size, void* d_ws, size_t ws_size,
                              hipStream_t stream) {
  const float* x     = (const float*)d_in[0];
  const float* off_w = (const float*)d_in[1];
  const float* off_b = (const float*)d_in[2];
  const float* mod_w = (const float*)d_in[3];
  const float* mod_b = (const float*)d_in[4];
  const float* w     = (const float*)d_in[5];
  const float* b     = (const float*)d_in[6];
  const float* gamma = (const float*)d_in[7];
  const float* beta  = (const float*)d_in[8];
  float* out = (float*)d_out;
  float* ws  = (float*)d_ws;

  float* offo  = ws + OFF_OFF;
  float* masko = ws + MASK_OFF;
  unsigned short* wbtA = (unsigned short*)(ws + WBTA_OFF);
  unsigned short* wbtB = (unsigned short*)(ws + WBTB_OFF);
  float* stat  = ws + STAT_OFF;

  prep_kernel<<<240, 256, 0, stream>>>(off_w, mod_w, w, wbtA, wbtB, stat);
  convA_mfma_kernel<<<1024, 256, 0, stream>>>(x, wbtA, off_b, mod_b, offo, masko);
  deform_mfma_kernel<<<1024, 256, 0, stream>>>(x, offo, masko, wbtB, b, out);
  stats2_kernel<<<1024, 256, 0, stream>>>(out, stat);
  bnrelu_kernel<<<8192, 256, 0, stream>>>(out, stat, gamma, beta);
}

// Round 9
// 246.377 us; speedup vs baseline: 2.3094x; 1.2072x over previous
//
#include <hip/hip_runtime.h>
#include <math.h>

// Problem constants: B=8, C=64 (in), OC=64 (out), H=W=128, K=3x3=9, PAD=1.
#define Hn 128
#define Wn 128
#define HW 16384
#define NPIX 131072
#define EPSv 1e-5f

// ws layout (floats)
#define XT_OFF   0            // x_t bf16 channels-last [b][y][x][c]: 8388608 shorts = 4194304 floats
#define OFF_OFF  4194304      // 8*18*16384 = 2359296
#define MASK_OFF 6553600      // 8*9*16384  = 1179648
#define WBTA_OFF 7733248      // 20480 shorts = 10240 floats
#define WBTB_OFF 7743488      // 40960 shorts = 20480 floats
#define STAT_OFF 7763968      // 128 (sum[64], sumsq[64])   -> total 7764096 floats = 31.1 MB

// K-packing: 640 = 4 c16-chunks x 5 tap-pairs x 32. K-elem e in [0,32):
//   tap = tp*2 + (e>>4)  (tap 9 = zero pad), c = chunk*16 + (e&15).
// R9: x_t channels-last bf16 -> 8 channels per dwordx4 gather.
// deform = R8-validated LDS-staged skeleton; convA = R8-validated direct-fragment.

typedef short s16x8 __attribute__((ext_vector_type(8)));
typedef unsigned short u16x4 __attribute__((ext_vector_type(4)));
typedef float f32x4 __attribute__((ext_vector_type(4)));

__device__ __forceinline__ unsigned short f2bf(float f) {
  unsigned u = __float_as_uint(f);
  return (unsigned short)((u + 0x7fffu + ((u >> 16) & 1u)) >> 16);  // RNE
}
__device__ __forceinline__ float bf2f(unsigned short s) {
  return __uint_as_float((unsigned)s << 16);
}

// ---------------- prep: pack weights into MFMA A-operand order; zero stat ----------------
__global__ __launch_bounds__(256) void prep_kernel(
    const float* __restrict__ off_w, const float* __restrict__ mod_w,
    const float* __restrict__ w, unsigned short* __restrict__ wbtA,
    unsigned short* __restrict__ wbtB, float* __restrict__ stat) {
  int i = blockIdx.x * 256 + threadIdx.x;
  if (i < 128) stat[i] = 0.f;
  if (i < 20480) {
    int e = i & 31, oc = (i >> 5) & 31, it = i >> 10;
    int tp = it % 5, chunk = it / 5;
    int tap = tp * 2 + (e >> 4);
    int c = (chunk << 4) + (e & 15);
    float v = 0.f;
    if (tap < 9) {
      if (oc < 18) v = off_w[(oc * 64 + c) * 9 + tap];
      else if (oc < 27) v = mod_w[((oc - 18) * 64 + c) * 9 + tap];
    }
    wbtA[i] = f2bf(v);
  } else if (i < 20480 + 40960) {
    int j = i - 20480;
    int e = j & 31, oc = (j >> 5) & 63, it = j >> 11;
    int tp = it % 5, chunk = it / 5;
    int tap = tp * 2 + (e >> 4);
    int c = (chunk << 4) + (e & 15);
    float v = (tap < 9) ? w[(oc * 64 + c) * 9 + tap] : 0.f;
    wbtB[j] = f2bf(v);
  }
}

// ---------------- xform: x (NCHW fp32) -> x_t (NHWC bf16) ----------------
__global__ __launch_bounds__(256) void xform_kernel(
    const float* __restrict__ x, unsigned short* __restrict__ xt) {
  int blk = blockIdx.x;                       // 512 blocks
  int b = blk & 7;
  int hw = ((blk >> 3) << 8) + threadIdx.x;   // 0..16383
  const float* xb = x + ((size_t)(b << 6) << 14) + hw;
  unsigned short* o = xt + (((size_t)(b << 14)) + hw) * 64;
#pragma unroll
  for (int g = 0; g < 8; ++g) {
    float v[8];
#pragma unroll
    for (int j = 0; j < 8; ++j) v[j] = xb[(size_t)((g << 3) + j) << 14];
    s16x8 pk;
#pragma unroll
    for (int j = 0; j < 8; ++j) pk[j] = (short)f2bf(v[j]);
    *(s16x8*)(o + (g << 3)) = pk;
  }
}

// ---------------- kernel A: offset+mask conv, direct-fragment MFMA from x_t ----------------
__global__ __launch_bounds__(256, 4) void convA_mfma_kernel(
    const unsigned short* __restrict__ xt, const unsigned short* __restrict__ wbtA,
    const float* __restrict__ off_b, const float* __restrict__ mod_b,
    float* __restrict__ off_out, float* __restrict__ mask_out) {
  int t = threadIdx.x;
  int bx = blockIdx.x;
  int b = bx & 7, h = bx >> 3;
  int ln = t & 15, quad = (t >> 4) & 3, wv = t >> 6;
  int p0 = (wv << 5) + ln, p1 = p0 + 16;
  int s_ = quad >> 1, cj = (quad & 1) << 3;

  f32x4 acc[2][2];
#pragma unroll
  for (int mt = 0; mt < 2; ++mt)
#pragma unroll
    for (int nt = 0; nt < 2; ++nt) acc[mt][nt] = (f32x4){0.f, 0.f, 0.f, 0.f};

  const unsigned short* xtb = xt + ((size_t)(b << 14)) * 64;

  for (int it = 0; it < 20; ++it) {
    int chunk = it / 5, tp = it - chunk * 5;
    int tap = tp * 2 + s_;
    s16x8 B0 = (s16x8){0, 0, 0, 0, 0, 0, 0, 0};
    s16x8 B1 = (s16x8){0, 0, 0, 0, 0, 0, 0, 0};
    if (tap < 9) {
      int gy = h + tap / 3 - 1;
      if (gy >= 0 && gy < Hn) {
        const unsigned short* rowp = xtb + ((size_t)(gy << 7)) * 64 + (chunk << 4) + cj;
        int gx0 = p0 + tap % 3 - 1;
        int gx1 = p1 + tap % 3 - 1;
        if (gx0 >= 0 && gx0 < Wn) B0 = *(const s16x8*)(rowp + (gx0 << 6));
        if (gx1 >= 0 && gx1 < Wn) B1 = *(const s16x8*)(rowp + (gx1 << 6));
      }
    }
#pragma unroll
    for (int mt = 0; mt < 2; ++mt) {
      s16x8 A = *(const s16x8*)(wbtA + (size_t)((it << 5) + (mt << 4) + ln) * 32 + (quad << 3));
      acc[mt][0] = __builtin_amdgcn_mfma_f32_16x16x32_bf16(A, B0, acc[mt][0], 0, 0, 0);
      acc[mt][1] = __builtin_amdgcn_mfma_f32_16x16x32_bf16(A, B1, acc[mt][1], 0, 0, 0);
    }
  }

  int hw = h << 7;
#pragma unroll
  for (int mt = 0; mt < 2; ++mt)
#pragma unroll
    for (int r = 0; r < 4; ++r) {
      int oc = (mt << 4) + (quad << 2) + r;
#pragma unroll
      for (int nt = 0; nt < 2; ++nt) {
        int px = (wv << 5) + (nt << 4) + ln;
        float val = acc[mt][nt][r];
        if (oc < 18) {
          off_out[(((size_t)b * 18 + oc) << 14) + hw + px] = val + off_b[oc];
        } else if (oc < 27) {
          float z = val + mod_b[oc - 18];
          mask_out[(((size_t)b * 9 + (oc - 18)) << 14) + hw + px] = 2.f / (1.f + expf(-z));
        }
      }
    }
}

// ---------------- kernel B: modulated deformable conv, R8 skeleton + x_t gathers ----------------
__global__ __launch_bounds__(256, 3) void deform_mfma_kernel(
    const unsigned short* __restrict__ xt, const float* __restrict__ off,
    const float* __restrict__ mask, const unsigned short* __restrict__ wbtB,
    const float* __restrict__ bias, float* __restrict__ y) {
  __shared__ short vlds[2 * 128 * 40];          // 20480 B
  __shared__ unsigned short geow[9 * 128 * 4];  // 9216 B: gy0,gy1,gx0,gx1 bf16 (mask folded)
  __shared__ unsigned short geoi[9 * 128];      // 2304 B: ibase = rbase*128+cbase (<=126 each)
  int t = threadIdx.x;
  int bx = blockIdx.x;
  int b = bx & 7, h = bx >> 3;
  int p = t & 127, half = t >> 7;
  int ln = t & 15, quad = (t >> 4) & 3, wv = t >> 6;
  int hw = h << 7;

  // ---- prologue: geometry for 128 px x 9 taps ----
  for (int i = t; i < 1152; i += 256) {
    int tap = i >> 7, p2 = i & 127;
    int ob = ((b * 18 + 2 * tap) << 14) + hw + p2;
    float dy = off[ob];
    float dx = off[ob + HW];
    float m = mask[((b * 9 + tap) << 14) + hw + p2];
    float py = dy + (float)(h + tap / 3 - 1);
    float pxf = dx + (float)(p2 + tap % 3 - 1);
    float y0f = floorf(py), x0f = floorf(pxf);
    float ly = py - y0f, lx = pxf - x0f;
    int y0 = (int)y0f, x0 = (int)x0f;
    int y1 = y0 + 1, x1 = x0 + 1;
    float fy0 = (y0 >= 0 && y0 < Hn) ? 1.f : 0.f;
    float fy1 = (y1 >= 0 && y1 < Hn) ? 1.f : 0.f;
    float fx0 = (x0 >= 0 && x0 < Wn) ? 1.f : 0.f;
    float fx1 = (x1 >= 0 && x1 < Wn) ? 1.f : 0.f;
    float ax0 = (1.f - lx) * fx0, ax1 = lx * fx1;          // -> cols cx0, cx1
    float ay0 = (1.f - ly) * fy0 * m, ay1 = ly * fy1 * m;  // -> rows cy0, cy1 (mask folded)
    int cy0 = min(max(y0, 0), Hn - 1), cy1 = min(max(y1, 0), Hn - 1);
    int cx0 = min(max(x0, 0), Wn - 1), cx1 = min(max(x1, 0), Wn - 1);
    int cbase = min(cx0, Wn - 2), rbase = min(cy0, Hn - 2);
    float gx0 = (cx0 == cbase ? ax0 : 0.f) + (cx1 == cbase ? ax1 : 0.f);
    float gx1 = (cx0 == cbase + 1 ? ax0 : 0.f) + (cx1 == cbase + 1 ? ax1 : 0.f);
    float gy0 = (cy0 == rbase ? ay0 : 0.f) + (cy1 == rbase ? ay1 : 0.f);
    float gy1 = (cy0 == rbase + 1 ? ay0 : 0.f) + (cy1 == rbase + 1 ? ay1 : 0.f);
    unsigned short* gw = geow + i * 4;
    gw[0] = f2bf(gy0);
    gw[1] = f2bf(gy1);
    gw[2] = f2bf(gx0);
    gw[3] = f2bf(gx1);
    geoi[i] = (unsigned short)((rbase << 7) + cbase);
  }
  __syncthreads();

  f32x4 acc[4][2];
#pragma unroll
  for (int mt = 0; mt < 4; ++mt)
#pragma unroll
    for (int nt = 0; nt < 2; ++nt) acc[mt][nt] = (f32x4){0.f, 0.f, 0.f, 0.f};

  const unsigned short* xtb = xt + ((size_t)(b << 14)) * 64;

  for (int it = 0; it < 20; ++it) {
    int chunk = it / 5, tp = it - chunk * 5;
    int ch0 = (chunk << 4) + (half << 3);
    // geometry for both taps
    float gy0[2], gy1[2], gx0[2], gx1[2];
    const unsigned short* cp[2];
#pragma unroll
    for (int s = 0; s < 2; ++s) {
      int tap = tp * 2 + s;
      if (tap < 9) {
        int gidx = (tap << 7) + p;
        u16x4 wq = *(const u16x4*)(geow + gidx * 4);
        unsigned ib = geoi[gidx];
        gy0[s] = bf2f(wq[0]);
        gy1[s] = bf2f(wq[1]);
        gx0[s] = bf2f(wq[2]);
        gx1[s] = bf2f(wq[3]);
        cp[s] = xtb + ((size_t)ib) * 64 + ch0;
      } else {
        cp[s] = xtb + ch0;  // dead
        gy0[s] = gy1[s] = gx0[s] = gx1[s] = 0.f;
      }
    }
    // batched corner loads: 2 taps x 4 corners x (8ch dwordx4)
    s16x8 c00[2], c01[2], c10[2], c11[2];
#pragma unroll
    for (int s = 0; s < 2; ++s) {
      int tap = tp * 2 + s;
      if (tap < 9) {
        c00[s] = *(const s16x8*)(cp[s]);
        c01[s] = *(const s16x8*)(cp[s] + 64);
        c10[s] = *(const s16x8*)(cp[s] + 8192);
        c11[s] = *(const s16x8*)(cp[s] + 8192 + 64);
      }
    }
    s16x8 pk[2];
#pragma unroll
    for (int s = 0; s < 2; ++s) {
      int tap = tp * 2 + s;
      if (tap < 9) {
#pragma unroll
        for (int j = 0; j < 8; ++j) {
          float v = gy0[s] * (gx0[s] * bf2f((unsigned short)c00[s][j]) +
                              gx1[s] * bf2f((unsigned short)c01[s][j])) +
                    gy1[s] * (gx0[s] * bf2f((unsigned short)c10[s][j]) +
                              gx1[s] * bf2f((unsigned short)c11[s][j]));
          pk[s][j] = (short)f2bf(v);
        }
      } else {
#pragma unroll
        for (int j = 0; j < 8; ++j) pk[s][j] = 0;
      }
    }
    short* vd = vlds + (it & 1) * 5120 + p * 40 + (half << 3);
    *(s16x8*)(vd) = pk[0];
    *(s16x8*)(vd + 16) = pk[1];
    __syncthreads();
    const short* vb = vlds + (it & 1) * 5120;
    s16x8 B0 = *(const s16x8*)(vb + ((wv << 5) + ln) * 40 + (quad << 3));
    s16x8 B1 = *(const s16x8*)(vb + ((wv << 5) + 16 + ln) * 40 + (quad << 3));
#pragma unroll
    for (int mt = 0; mt < 4; ++mt) {
      s16x8 A = *(const s16x8*)(wbtB + (size_t)((it << 6) + (mt << 4) + ln) * 32 + (quad << 3));
      acc[mt][0] = __builtin_amdgcn_mfma_f32_16x16x32_bf16(A, B0, acc[mt][0], 0, 0, 0);
      acc[mt][1] = __builtin_amdgcn_mfma_f32_16x16x32_bf16(A, B1, acc[mt][1], 0, 0, 0);
    }
  }

#pragma unroll
  for (int mt = 0; mt < 4; ++mt)
#pragma unroll
    for (int r = 0; r < 4; ++r) {
      int oc = (mt << 4) + (quad << 2) + r;
      float bv = bias[oc];
      float* yp = y + (((size_t)(b << 6) + oc) << 14) + hw;
      yp[(wv << 5) + ln] = acc[mt][0][r] + bv;
      yp[(wv << 5) + 16 + ln] = acc[mt][1][r] + bv;
    }
}

// ---------------- kernel C: per-channel sum/sumsq (sliced, atomics into stat) ----------------
__global__ __launch_bounds__(256) void stats2_kernel(
    const float* __restrict__ y, float* __restrict__ stat) {
  int bxx = blockIdx.x;            // 1024 = 64 ch x 16 slices
  int c = bxx & 63, sl = bxx >> 6;
  int bb = sl >> 1;
  const float4* yp = (const float4*)(y + (((size_t)bb * 64 + c) << 14) + ((sl & 1) << 13));
  float s = 0.f, ss = 0.f;
  for (int i = threadIdx.x; i < 2048; i += 256) {
    float4 v = yp[i];
    s += v.x + v.y + v.z + v.w;
    ss += v.x * v.x + v.y * v.y + v.z * v.z + v.w * v.w;
  }
#pragma unroll
  for (int o = 32; o > 0; o >>= 1) {
    s += __shfl_xor(s, o);
    ss += __shfl_xor(ss, o);
  }
  __shared__ float shs[4], shss[4];
  int lane = threadIdx.x & 63, wv = threadIdx.x >> 6;
  if (lane == 0) { shs[wv] = s; shss[wv] = ss; }
  __syncthreads();
  if (threadIdx.x == 0) {
    float S = shs[0] + shs[1] + shs[2] + shs[3];
    float SS = shss[0] + shss[1] + shss[2] + shss[3];
    atomicAdd(stat + c, S);
    atomicAdd(stat + 64 + c, SS);
  }
}

// ---------------- kernel D: batchnorm scale/shift + relu, in place ----------------
__global__ __launch_bounds__(256) void bnrelu_kernel(
    float* __restrict__ y, const float* __restrict__ stat,
    const float* __restrict__ gamma, const float* __restrict__ beta) {
  float4* y4 = (float4*)y;
  for (int i = blockIdx.x * 256 + threadIdx.x; i < 2097152; i += gridDim.x * 256) {
    int c = (i >> 12) & 63;
    float mean = stat[c] * (1.f / (float)NPIX);
    float var = stat[64 + c] * (1.f / (float)NPIX) - mean * mean;
    float r = rsqrtf(var + EPSv);
    float g = gamma[c] * r;
    float bt = beta[c] - mean * g;
    float4 v = y4[i];
    v.x = fmaxf(v.x * g + bt, 0.f);
    v.y = fmaxf(v.y * g + bt, 0.f);
    v.z = fmaxf(v.z * g + bt, 0.f);
    v.w = fmaxf(v.w * g + bt, 0.f);
    y4[i] = v;
  }
}

extern "C" void kernel_launch(void* const* d_in, const int* in_sizes, int n_in,
                              void* d_out, int out_size, void* d_ws, size_t ws_size,
                              hipStream_t stream) {
  const float* x     = (const float*)d_in[0];
  const float* off_w = (const float*)d_in[1];
  const float* off_b = (const float*)d_in[2];
  const float* mod_w = (const float*)d_in[3];
  const float* mod_b = (const float*)d_in[4];
  const float* w     = (const float*)d_in[5];
  const float* b     = (const float*)d_in[6];
  const float* gamma = (const float*)d_in[7];
  const float* beta  = (const float*)d_in[8];
  float* out = (float*)d_out;
  float* ws  = (float*)d_ws;

  unsigned short* xt  = (unsigned short*)(ws + XT_OFF);
  float* offo  = ws + OFF_OFF;
  float* masko = ws + MASK_OFF;
  unsigned short* wbtA = (unsigned short*)(ws + WBTA_OFF);
  unsigned short* wbtB = (unsigned short*)(ws + WBTB_OFF);
  float* stat  = ws + STAT_OFF;

  prep_kernel<<<240, 256, 0, stream>>>(off_w, mod_w, w, wbtA, wbtB, stat);
  xform_kernel<<<512, 256, 0, stream>>>(x, xt);
  convA_mfma_kernel<<<1024, 256, 0, stream>>>(xt, wbtA, off_b, mod_b, offo, masko);
  deform_mfma_kernel<<<1024, 256, 0, stream>>>(xt, offo, masko, wbtB, b, out);
  stats2_kernel<<<1024, 256, 0, stream>>>(out, stat);
  bnrelu_kernel<<<8192, 256, 0, stream>>>(out, stat, gamma, beta);
}

// Round 10
// 245.728 us; speedup vs baseline: 2.3155x; 1.0026x over previous
//
#include <hip/hip_runtime.h>
#include <math.h>

// Problem constants: B=8, C=64 (in), OC=64 (out), H=W=128, K=3x3=9, PAD=1.
#define Hn 128
#define Wn 128
#define HW 16384
#define NPIX 131072
#define EPSv 1e-5f

// ws layout (floats)
#define XT_OFF   0            // x_t bf16 channels-last [b][y][x][c]: 8388608 shorts = 4194304 floats
#define OFF_OFF  4194304      // 8*18*16384 = 2359296
#define MASK_OFF 6553600      // 8*9*16384  = 1179648
#define WBTA_OFF 7733248      // 20480 shorts = 10240 floats
#define WBTB_OFF 7743488      // 40960 shorts = 20480 floats
#define STAT_OFF 7763968      // 128 (sum[64], sumsq[64])   -> total 7764096 floats = 31.1 MB

// K-packing: 640 = 4 c16-chunks x 5 tap-pairs x 32. K-elem e in [0,32):
//   tap = tp*2 + (e>>4)  (tap 9 = zero pad), c = chunk*16 + (e&15).
// R10: identical to R9 except occupancy caps lifted: deform (256,3)->(256,5)
// (VGPR 52, LDS 31.5KB both allow 5 blocks/CU), convA (256,4)->(256,6).

typedef short s16x8 __attribute__((ext_vector_type(8)));
typedef unsigned short u16x4 __attribute__((ext_vector_type(4)));
typedef float f32x4 __attribute__((ext_vector_type(4)));

__device__ __forceinline__ unsigned short f2bf(float f) {
  unsigned u = __float_as_uint(f);
  return (unsigned short)((u + 0x7fffu + ((u >> 16) & 1u)) >> 16);  // RNE
}
__device__ __forceinline__ float bf2f(unsigned short s) {
  return __uint_as_float((unsigned)s << 16);
}

// ---------------- prep: pack weights into MFMA A-operand order; zero stat ----------------
__global__ __launch_bounds__(256) void prep_kernel(
    const float* __restrict__ off_w, const float* __restrict__ mod_w,
    const float* __restrict__ w, unsigned short* __restrict__ wbtA,
    unsigned short* __restrict__ wbtB, float* __restrict__ stat) {
  int i = blockIdx.x * 256 + threadIdx.x;
  if (i < 128) stat[i] = 0.f;
  if (i < 20480) {
    int e = i & 31, oc = (i >> 5) & 31, it = i >> 10;
    int tp = it % 5, chunk = it / 5;
    int tap = tp * 2 + (e >> 4);
    int c = (chunk << 4) + (e & 15);
    float v = 0.f;
    if (tap < 9) {
      if (oc < 18) v = off_w[(oc * 64 + c) * 9 + tap];
      else if (oc < 27) v = mod_w[((oc - 18) * 64 + c) * 9 + tap];
    }
    wbtA[i] = f2bf(v);
  } else if (i < 20480 + 40960) {
    int j = i - 20480;
    int e = j & 31, oc = (j >> 5) & 63, it = j >> 11;
    int tp = it % 5, chunk = it / 5;
    int tap = tp * 2 + (e >> 4);
    int c = (chunk << 4) + (e & 15);
    float v = (tap < 9) ? w[(oc * 64 + c) * 9 + tap] : 0.f;
    wbtB[j] = f2bf(v);
  }
}

// ---------------- xform: x (NCHW fp32) -> x_t (NHWC bf16) ----------------
__global__ __launch_bounds__(256) void xform_kernel(
    const float* __restrict__ x, unsigned short* __restrict__ xt) {
  int blk = blockIdx.x;                       // 512 blocks
  int b = blk & 7;
  int hw = ((blk >> 3) << 8) + threadIdx.x;   // 0..16383
  const float* xb = x + ((size_t)(b << 6) << 14) + hw;
  unsigned short* o = xt + (((size_t)(b << 14)) + hw) * 64;
#pragma unroll
  for (int g = 0; g < 8; ++g) {
    float v[8];
#pragma unroll
    for (int j = 0; j < 8; ++j) v[j] = xb[(size_t)((g << 3) + j) << 14];
    s16x8 pk;
#pragma unroll
    for (int j = 0; j < 8; ++j) pk[j] = (short)f2bf(v[j]);
    *(s16x8*)(o + (g << 3)) = pk;
  }
}

// ---------------- kernel A: offset+mask conv, direct-fragment MFMA from x_t ----------------
__global__ __launch_bounds__(256, 6) void convA_mfma_kernel(
    const unsigned short* __restrict__ xt, const unsigned short* __restrict__ wbtA,
    const float* __restrict__ off_b, const float* __restrict__ mod_b,
    float* __restrict__ off_out, float* __restrict__ mask_out) {
  int t = threadIdx.x;
  int bx = blockIdx.x;
  int b = bx & 7, h = bx >> 3;
  int ln = t & 15, quad = (t >> 4) & 3, wv = t >> 6;
  int p0 = (wv << 5) + ln, p1 = p0 + 16;
  int s_ = quad >> 1, cj = (quad & 1) << 3;

  f32x4 acc[2][2];
#pragma unroll
  for (int mt = 0; mt < 2; ++mt)
#pragma unroll
    for (int nt = 0; nt < 2; ++nt) acc[mt][nt] = (f32x4){0.f, 0.f, 0.f, 0.f};

  const unsigned short* xtb = xt + ((size_t)(b << 14)) * 64;

  for (int it = 0; it < 20; ++it) {
    int chunk = it / 5, tp = it - chunk * 5;
    int tap = tp * 2 + s_;
    s16x8 B0 = (s16x8){0, 0, 0, 0, 0, 0, 0, 0};
    s16x8 B1 = (s16x8){0, 0, 0, 0, 0, 0, 0, 0};
    if (tap < 9) {
      int gy = h + tap / 3 - 1;
      if (gy >= 0 && gy < Hn) {
        const unsigned short* rowp = xtb + ((size_t)(gy << 7)) * 64 + (chunk << 4) + cj;
        int gx0 = p0 + tap % 3 - 1;
        int gx1 = p1 + tap % 3 - 1;
        if (gx0 >= 0 && gx0 < Wn) B0 = *(const s16x8*)(rowp + (gx0 << 6));
        if (gx1 >= 0 && gx1 < Wn) B1 = *(const s16x8*)(rowp + (gx1 << 6));
      }
    }
#pragma unroll
    for (int mt = 0; mt < 2; ++mt) {
      s16x8 A = *(const s16x8*)(wbtA + (size_t)((it << 5) + (mt << 4) + ln) * 32 + (quad << 3));
      acc[mt][0] = __builtin_amdgcn_mfma_f32_16x16x32_bf16(A, B0, acc[mt][0], 0, 0, 0);
      acc[mt][1] = __builtin_amdgcn_mfma_f32_16x16x32_bf16(A, B1, acc[mt][1], 0, 0, 0);
    }
  }

  int hw = h << 7;
#pragma unroll
  for (int mt = 0; mt < 2; ++mt)
#pragma unroll
    for (int r = 0; r < 4; ++r) {
      int oc = (mt << 4) + (quad << 2) + r;
#pragma unroll
      for (int nt = 0; nt < 2; ++nt) {
        int px = (wv << 5) + (nt << 4) + ln;
        float val = acc[mt][nt][r];
        if (oc < 18) {
          off_out[(((size_t)b * 18 + oc) << 14) + hw + px] = val + off_b[oc];
        } else if (oc < 27) {
          float z = val + mod_b[oc - 18];
          mask_out[(((size_t)b * 9 + (oc - 18)) << 14) + hw + px] = 2.f / (1.f + expf(-z));
        }
      }
    }
}

// ---------------- kernel B: modulated deformable conv, R8 skeleton + x_t gathers ----------------
__global__ __launch_bounds__(256, 5) void deform_mfma_kernel(
    const unsigned short* __restrict__ xt, const float* __restrict__ off,
    const float* __restrict__ mask, const unsigned short* __restrict__ wbtB,
    const float* __restrict__ bias, float* __restrict__ y) {
  __shared__ short vlds[2 * 128 * 40];          // 20480 B
  __shared__ unsigned short geow[9 * 128 * 4];  // 9216 B: gy0,gy1,gx0,gx1 bf16 (mask folded)
  __shared__ unsigned short geoi[9 * 128];      // 2304 B: ibase = rbase*128+cbase (<=126 each)
  int t = threadIdx.x;
  int bx = blockIdx.x;
  int b = bx & 7, h = bx >> 3;
  int p = t & 127, half = t >> 7;
  int ln = t & 15, quad = (t >> 4) & 3, wv = t >> 6;
  int hw = h << 7;

  // ---- prologue: geometry for 128 px x 9 taps ----
  for (int i = t; i < 1152; i += 256) {
    int tap = i >> 7, p2 = i & 127;
    int ob = ((b * 18 + 2 * tap) << 14) + hw + p2;
    float dy = off[ob];
    float dx = off[ob + HW];
    float m = mask[((b * 9 + tap) << 14) + hw + p2];
    float py = dy + (float)(h + tap / 3 - 1);
    float pxf = dx + (float)(p2 + tap % 3 - 1);
    float y0f = floorf(py), x0f = floorf(pxf);
    float ly = py - y0f, lx = pxf - x0f;
    int y0 = (int)y0f, x0 = (int)x0f;
    int y1 = y0 + 1, x1 = x0 + 1;
    float fy0 = (y0 >= 0 && y0 < Hn) ? 1.f : 0.f;
    float fy1 = (y1 >= 0 && y1 < Hn) ? 1.f : 0.f;
    float fx0 = (x0 >= 0 && x0 < Wn) ? 1.f : 0.f;
    float fx1 = (x1 >= 0 && x1 < Wn) ? 1.f : 0.f;
    float ax0 = (1.f - lx) * fx0, ax1 = lx * fx1;          // -> cols cx0, cx1
    float ay0 = (1.f - ly) * fy0 * m, ay1 = ly * fy1 * m;  // -> rows cy0, cy1 (mask folded)
    int cy0 = min(max(y0, 0), Hn - 1), cy1 = min(max(y1, 0), Hn - 1);
    int cx0 = min(max(x0, 0), Wn - 1), cx1 = min(max(x1, 0), Wn - 1);
    int cbase = min(cx0, Wn - 2), rbase = min(cy0, Hn - 2);
    float gx0 = (cx0 == cbase ? ax0 : 0.f) + (cx1 == cbase ? ax1 : 0.f);
    float gx1 = (cx0 == cbase + 1 ? ax0 : 0.f) + (cx1 == cbase + 1 ? ax1 : 0.f);
    float gy0 = (cy0 == rbase ? ay0 : 0.f) + (cy1 == rbase ? ay1 : 0.f);
    float gy1 = (cy0 == rbase + 1 ? ay0 : 0.f) + (cy1 == rbase + 1 ? ay1 : 0.f);
    unsigned short* gw = geow + i * 4;
    gw[0] = f2bf(gy0);
    gw[1] = f2bf(gy1);
    gw[2] = f2bf(gx0);
    gw[3] = f2bf(gx1);
    geoi[i] = (unsigned short)((rbase << 7) + cbase);
  }
  __syncthreads();

  f32x4 acc[4][2];
#pragma unroll
  for (int mt = 0; mt < 4; ++mt)
#pragma unroll
    for (int nt = 0; nt < 2; ++nt) acc[mt][nt] = (f32x4){0.f, 0.f, 0.f, 0.f};

  const unsigned short* xtb = xt + ((size_t)(b << 14)) * 64;

  for (int it = 0; it < 20; ++it) {
    int chunk = it / 5, tp = it - chunk * 5;
    int ch0 = (chunk << 4) + (half << 3);
    // geometry for both taps
    float gy0[2], gy1[2], gx0[2], gx1[2];
    const unsigned short* cp[2];
#pragma unroll
    for (int s = 0; s < 2; ++s) {
      int tap = tp * 2 + s;
      if (tap < 9) {
        int gidx = (tap << 7) + p;
        u16x4 wq = *(const u16x4*)(geow + gidx * 4);
        unsigned ib = geoi[gidx];
        gy0[s] = bf2f(wq[0]);
        gy1[s] = bf2f(wq[1]);
        gx0[s] = bf2f(wq[2]);
        gx1[s] = bf2f(wq[3]);
        cp[s] = xtb + ((size_t)ib) * 64 + ch0;
      } else {
        cp[s] = xtb + ch0;  // dead
        gy0[s] = gy1[s] = gx0[s] = gx1[s] = 0.f;
      }
    }
    // batched corner loads: 2 taps x 4 corners x (8ch dwordx4)
    s16x8 c00[2], c01[2], c10[2], c11[2];
#pragma unroll
    for (int s = 0; s < 2; ++s) {
      int tap = tp * 2 + s;
      if (tap < 9) {
        c00[s] = *(const s16x8*)(cp[s]);
        c01[s] = *(const s16x8*)(cp[s] + 64);
        c10[s] = *(const s16x8*)(cp[s] + 8192);
        c11[s] = *(const s16x8*)(cp[s] + 8192 + 64);
      }
    }
    s16x8 pk[2];
#pragma unroll
    for (int s = 0; s < 2; ++s) {
      int tap = tp * 2 + s;
      if (tap < 9) {
#pragma unroll
        for (int j = 0; j < 8; ++j) {
          float v = gy0[s] * (gx0[s] * bf2f((unsigned short)c00[s][j]) +
                              gx1[s] * bf2f((unsigned short)c01[s][j])) +
                    gy1[s] * (gx0[s] * bf2f((unsigned short)c10[s][j]) +
                              gx1[s] * bf2f((unsigned short)c11[s][j]));
          pk[s][j] = (short)f2bf(v);
        }
      } else {
#pragma unroll
        for (int j = 0; j < 8; ++j) pk[s][j] = 0;
      }
    }
    short* vd = vlds + (it & 1) * 5120 + p * 40 + (half << 3);
    *(s16x8*)(vd) = pk[0];
    *(s16x8*)(vd + 16) = pk[1];
    __syncthreads();
    const short* vb = vlds + (it & 1) * 5120;
    s16x8 B0 = *(const s16x8*)(vb + ((wv << 5) + ln) * 40 + (quad << 3));
    s16x8 B1 = *(const s16x8*)(vb + ((wv << 5) + 16 + ln) * 40 + (quad << 3));
#pragma unroll
    for (int mt = 0; mt < 4; ++mt) {
      s16x8 A = *(const s16x8*)(wbtB + (size_t)((it << 6) + (mt << 4) + ln) * 32 + (quad << 3));
      acc[mt][0] = __builtin_amdgcn_mfma_f32_16x16x32_bf16(A, B0, acc[mt][0], 0, 0, 0);
      acc[mt][1] = __builtin_amdgcn_mfma_f32_16x16x32_bf16(A, B1, acc[mt][1], 0, 0, 0);
    }
  }

#pragma unroll
  for (int mt = 0; mt < 4; ++mt)
#pragma unroll
    for (int r = 0; r < 4; ++r) {
      int oc = (mt << 4) + (quad << 2) + r;
      float bv = bias[oc];
      float* yp = y + (((size_t)(b << 6) + oc) << 14) + hw;
      yp[(wv << 5) + ln] = acc[mt][0][r] + bv;
      yp[(wv << 5) + 16 + ln] = acc[mt][1][r] + bv;
    }
}

// ---------------- kernel C: per-channel sum/sumsq (sliced, atomics into stat) ----------------
__global__ __launch_bounds__(256) void stats2_kernel(
    const float* __restrict__ y, float* __restrict__ stat) {
  int bxx = blockIdx.x;            // 1024 = 64 ch x 16 slices
  int c = bxx & 63, sl = bxx >> 6;
  int bb = sl >> 1;
  const float4* yp = (const float4*)(y + (((size_t)bb * 64 + c) << 14) + ((sl & 1) << 13));
  float s = 0.f, ss = 0.f;
  for (int i = threadIdx.x; i < 2048; i += 256) {
    float4 v = yp[i];
    s += v.x + v.y + v.z + v.w;
    ss += v.x * v.x + v.y * v.y + v.z * v.z + v.w * v.w;
  }
#pragma unroll
  for (int o = 32; o > 0; o >>= 1) {
    s += __shfl_xor(s, o);
    ss += __shfl_xor(ss, o);
  }
  __shared__ float shs[4], shss[4];
  int lane = threadIdx.x & 63, wv = threadIdx.x >> 6;
  if (lane == 0) { shs[wv] = s; shss[wv] = ss; }
  __syncthreads();
  if (threadIdx.x == 0) {
    float S = shs[0] + shs[1] + shs[2] + shs[3];
    float SS = shss[0] + shss[1] + shss[2] + shss[3];
    atomicAdd(stat + c, S);
    atomicAdd(stat + 64 + c, SS);
  }
}

// ---------------- kernel D: batchnorm scale/shift + relu, in place ----------------
__global__ __launch_bounds__(256) void bnrelu_kernel(
    float* __restrict__ y, const float* __restrict__ stat,
    const float* __restrict__ gamma, const float* __restrict__ beta) {
  float4* y4 = (float4*)y;
  for (int i = blockIdx.x * 256 + threadIdx.x; i < 2097152; i += gridDim.x * 256) {
    int c = (i >> 12) & 63;
    float mean = stat[c] * (1.f / (float)NPIX);
    float var = stat[64 + c] * (1.f / (float)NPIX) - mean * mean;
    float r = rsqrtf(var + EPSv);
    float g = gamma[c] * r;
    float bt = beta[c] - mean * g;
    float4 v = y4[i];
    v.x = fmaxf(v.x * g + bt, 0.f);
    v.y = fmaxf(v.y * g + bt, 0.f);
    v.z = fmaxf(v.z * g + bt, 0.f);
    v.w = fmaxf(v.w * g + bt, 0.f);
    y4[i] = v;
  }
}

extern "C" void kernel_launch(void* const* d_in, const int* in_sizes, int n_in,
                              void* d_out, int out_size, void* d_ws, size_t ws_size,
                              hipStream_t stream) {
  const float* x     = (const float*)d_in[0];
  const float* off_w = (const float*)d_in[1];
  const float* off_b = (const float*)d_in[2];
  const float* mod_w = (const float*)d_in[3];
  const float* mod_b = (const float*)d_in[4];
  const float* w     = (const float*)d_in[5];
  const float* b     = (const float*)d_in[6];
  const float* gamma = (const float*)d_in[7];
  const float* beta  = (const float*)d_in[8];
  float* out = (float*)d_out;
  float* ws  = (float*)d_ws;

  unsigned short* xt  = (unsigned short*)(ws + XT_OFF);
  float* offo  = ws + OFF_OFF;
  float* masko = ws + MASK_OFF;
  unsigned short* wbtA = (unsigned short*)(ws + WBTA_OFF);
  unsigned short* wbtB = (unsigned short*)(ws + WBTB_OFF);
  float* stat  = ws + STAT_OFF;

  prep_kernel<<<240, 256, 0, stream>>>(off_w, mod_w, w, wbtA, wbtB, stat);
  xform_kernel<<<512, 256, 0, stream>>>(x, xt);
  convA_mfma_kernel<<<1024, 256, 0, stream>>>(xt, wbtA, off_b, mod_b, offo, masko);
  deform_mfma_kernel<<<1024, 256, 0, stream>>>(xt, offo, masko, wbtB, b, out);
  stats2_kernel<<<1024, 256, 0, stream>>>(out, stat);
  bnrelu_kernel<<<8192, 256, 0, stream>>>(out, stat, gamma, beta);
}

// Round 11
// 240.009 us; speedup vs baseline: 2.3707x; 1.0238x over previous
//
#include <hip/hip_runtime.h>
#include <math.h>

// Problem constants: B=8, C=64 (in), OC=64 (out), H=W=128, K=3x3=9, PAD=1.
#define Hn 128
#define Wn 128
#define HW 16384
#define NPIX 131072
#define EPSv 1e-5f

// ws layout (floats)
#define XT_OFF   0            // x_t bf16 channels-last [b][y][x][c]: 8388608 shorts = 4194304 floats
#define OFF_OFF  4194304      // 8*18*16384 = 2359296
#define MASK_OFF 6553600      // 8*9*16384  = 1179648
#define WBTA_OFF 7733248      // 20480 shorts = 10240 floats
#define WBTB_OFF 7743488      // 40960 shorts = 20480 floats
#define STAT_OFF 7763968      // 128 (sum[64], sumsq[64])   -> total 7764096 floats = 31.1 MB

// K-packing: 640 = 4 c16-chunks x 5 tap-pairs x 32. K-elem e in [0,32):
//   tap = tp*2 + (e>>4)  (tap 9 = zero pad), c = chunk*16 + (e&15).
// R11: vlds staging made WAVE-PRIVATE (lane->px remap pb = wv*32+(lane&31),
// half = lane>>5 writes exactly the rows wave wv's MFMA reads) -> the K-loop
// __syncthreads is deleted; same-wave ds ordering via compiler lgkmcnt.
// Addresses and values in vlds are bitwise identical to R10; only the writing
// thread changed. + unroll 2 (deform) / unroll 5 (convA) to deepen pipelines.

typedef short s16x8 __attribute__((ext_vector_type(8)));
typedef unsigned short u16x4 __attribute__((ext_vector_type(4)));
typedef float f32x4 __attribute__((ext_vector_type(4)));

__device__ __forceinline__ unsigned short f2bf(float f) {
  unsigned u = __float_as_uint(f);
  return (unsigned short)((u + 0x7fffu + ((u >> 16) & 1u)) >> 16);  // RNE
}
__device__ __forceinline__ float bf2f(unsigned short s) {
  return __uint_as_float((unsigned)s << 16);
}

// ---------------- prep: pack weights into MFMA A-operand order; zero stat ----------------
__global__ __launch_bounds__(256) void prep_kernel(
    const float* __restrict__ off_w, const float* __restrict__ mod_w,
    const float* __restrict__ w, unsigned short* __restrict__ wbtA,
    unsigned short* __restrict__ wbtB, float* __restrict__ stat) {
  int i = blockIdx.x * 256 + threadIdx.x;
  if (i < 128) stat[i] = 0.f;
  if (i < 20480) {
    int e = i & 31, oc = (i >> 5) & 31, it = i >> 10;
    int tp = it % 5, chunk = it / 5;
    int tap = tp * 2 + (e >> 4);
    int c = (chunk << 4) + (e & 15);
    float v = 0.f;
    if (tap < 9) {
      if (oc < 18) v = off_w[(oc * 64 + c) * 9 + tap];
      else if (oc < 27) v = mod_w[((oc - 18) * 64 + c) * 9 + tap];
    }
    wbtA[i] = f2bf(v);
  } else if (i < 20480 + 40960) {
    int j = i - 20480;
    int e = j & 31, oc = (j >> 5) & 63, it = j >> 11;
    int tp = it % 5, chunk = it / 5;
    int tap = tp * 2 + (e >> 4);
    int c = (chunk << 4) + (e & 15);
    float v = (tap < 9) ? w[(oc * 64 + c) * 9 + tap] : 0.f;
    wbtB[j] = f2bf(v);
  }
}

// ---------------- xform: x (NCHW fp32) -> x_t (NHWC bf16) ----------------
__global__ __launch_bounds__(256) void xform_kernel(
    const float* __restrict__ x, unsigned short* __restrict__ xt) {
  int blk = blockIdx.x;                       // 512 blocks
  int b = blk & 7;
  int hw = ((blk >> 3) << 8) + threadIdx.x;   // 0..16383
  const float* xb = x + ((size_t)(b << 6) << 14) + hw;
  unsigned short* o = xt + (((size_t)(b << 14)) + hw) * 64;
#pragma unroll
  for (int g = 0; g < 8; ++g) {
    float v[8];
#pragma unroll
    for (int j = 0; j < 8; ++j) v[j] = xb[(size_t)((g << 3) + j) << 14];
    s16x8 pk;
#pragma unroll
    for (int j = 0; j < 8; ++j) pk[j] = (short)f2bf(v[j]);
    *(s16x8*)(o + (g << 3)) = pk;
  }
}

// ---------------- kernel A: offset+mask conv, direct-fragment MFMA from x_t ----------------
__global__ __launch_bounds__(256, 4) void convA_mfma_kernel(
    const unsigned short* __restrict__ xt, const unsigned short* __restrict__ wbtA,
    const float* __restrict__ off_b, const float* __restrict__ mod_b,
    float* __restrict__ off_out, float* __restrict__ mask_out) {
  int t = threadIdx.x;
  int bx = blockIdx.x;
  int b = bx & 7, h = bx >> 3;
  int ln = t & 15, quad = (t >> 4) & 3, wv = t >> 6;
  int p0 = (wv << 5) + ln, p1 = p0 + 16;
  int s_ = quad >> 1, cj = (quad & 1) << 3;

  f32x4 acc[2][2];
#pragma unroll
  for (int mt = 0; mt < 2; ++mt)
#pragma unroll
    for (int nt = 0; nt < 2; ++nt) acc[mt][nt] = (f32x4){0.f, 0.f, 0.f, 0.f};

  const unsigned short* xtb = xt + ((size_t)(b << 14)) * 64;

#pragma unroll 5
  for (int it = 0; it < 20; ++it) {
    int chunk = it / 5, tp = it - chunk * 5;
    int tap = tp * 2 + s_;
    s16x8 B0 = (s16x8){0, 0, 0, 0, 0, 0, 0, 0};
    s16x8 B1 = (s16x8){0, 0, 0, 0, 0, 0, 0, 0};
    if (tap < 9) {
      int gy = h + tap / 3 - 1;
      if (gy >= 0 && gy < Hn) {
        const unsigned short* rowp = xtb + ((size_t)(gy << 7)) * 64 + (chunk << 4) + cj;
        int gx0 = p0 + tap % 3 - 1;
        int gx1 = p1 + tap % 3 - 1;
        if (gx0 >= 0 && gx0 < Wn) B0 = *(const s16x8*)(rowp + (gx0 << 6));
        if (gx1 >= 0 && gx1 < Wn) B1 = *(const s16x8*)(rowp + (gx1 << 6));
      }
    }
#pragma unroll
    for (int mt = 0; mt < 2; ++mt) {
      s16x8 A = *(const s16x8*)(wbtA + (size_t)((it << 5) + (mt << 4) + ln) * 32 + (quad << 3));
      acc[mt][0] = __builtin_amdgcn_mfma_f32_16x16x32_bf16(A, B0, acc[mt][0], 0, 0, 0);
      acc[mt][1] = __builtin_amdgcn_mfma_f32_16x16x32_bf16(A, B1, acc[mt][1], 0, 0, 0);
    }
  }

  int hw = h << 7;
#pragma unroll
  for (int mt = 0; mt < 2; ++mt)
#pragma unroll
    for (int r = 0; r < 4; ++r) {
      int oc = (mt << 4) + (quad << 2) + r;
#pragma unroll
      for (int nt = 0; nt < 2; ++nt) {
        int px = (wv << 5) + (nt << 4) + ln;
        float val = acc[mt][nt][r];
        if (oc < 18) {
          off_out[(((size_t)b * 18 + oc) << 14) + hw + px] = val + off_b[oc];
        } else if (oc < 27) {
          float z = val + mod_b[oc - 18];
          mask_out[(((size_t)b * 9 + (oc - 18)) << 14) + hw + px] = 2.f / (1.f + expf(-z));
        }
      }
    }
}

// ---------------- kernel B: modulated deformable conv, wave-private staging, no K-loop barrier ----------------
__global__ __launch_bounds__(256, 3) void deform_mfma_kernel(
    const unsigned short* __restrict__ xt, const float* __restrict__ off,
    const float* __restrict__ mask, const unsigned short* __restrict__ wbtB,
    const float* __restrict__ bias, float* __restrict__ y) {
  __shared__ short vlds[2 * 128 * 40];          // 20480 B, wave wv owns rows [wv*32, wv*32+32)
  __shared__ unsigned short geow[9 * 128 * 4];  // 9216 B: gy0,gy1,gx0,gx1 bf16 (mask folded)
  __shared__ unsigned short geoi[9 * 128];      // 2304 B: ibase = rbase*128+cbase (<=126 each)
  int t = threadIdx.x;
  int bx = blockIdx.x;
  int b = bx & 7, h = bx >> 3;
  int lane = t & 63, wv = t >> 6;
  int l4 = lane & 15, quad = (lane >> 4) & 3;
  int pb = (wv << 5) + (lane & 31);   // px this lane stages (within wave's own rows)
  int halfb = lane >> 5;              // which 8c of the 16c chunk this lane stages
  int hw = h << 7;

  // ---- prologue: geometry for 128 px x 9 taps ----
  for (int i = t; i < 1152; i += 256) {
    int tap = i >> 7, p2 = i & 127;
    int ob = ((b * 18 + 2 * tap) << 14) + hw + p2;
    float dy = off[ob];
    float dx = off[ob + HW];
    float m = mask[((b * 9 + tap) << 14) + hw + p2];
    float py = dy + (float)(h + tap / 3 - 1);
    float pxf = dx + (float)(p2 + tap % 3 - 1);
    float y0f = floorf(py), x0f = floorf(pxf);
    float ly = py - y0f, lx = pxf - x0f;
    int y0 = (int)y0f, x0 = (int)x0f;
    int y1 = y0 + 1, x1 = x0 + 1;
    float fy0 = (y0 >= 0 && y0 < Hn) ? 1.f : 0.f;
    float fy1 = (y1 >= 0 && y1 < Hn) ? 1.f : 0.f;
    float fx0 = (x0 >= 0 && x0 < Wn) ? 1.f : 0.f;
    float fx1 = (x1 >= 0 && x1 < Wn) ? 1.f : 0.f;
    float ax0 = (1.f - lx) * fx0, ax1 = lx * fx1;          // -> cols cx0, cx1
    float ay0 = (1.f - ly) * fy0 * m, ay1 = ly * fy1 * m;  // -> rows cy0, cy1 (mask folded)
    int cy0 = min(max(y0, 0), Hn - 1), cy1 = min(max(y1, 0), Hn - 1);
    int cx0 = min(max(x0, 0), Wn - 1), cx1 = min(max(x1, 0), Wn - 1);
    int cbase = min(cx0, Wn - 2), rbase = min(cy0, Hn - 2);
    float gx0 = (cx0 == cbase ? ax0 : 0.f) + (cx1 == cbase ? ax1 : 0.f);
    float gx1 = (cx0 == cbase + 1 ? ax0 : 0.f) + (cx1 == cbase + 1 ? ax1 : 0.f);
    float gy0 = (cy0 == rbase ? ay0 : 0.f) + (cy1 == rbase ? ay1 : 0.f);
    float gy1 = (cy0 == rbase + 1 ? ay0 : 0.f) + (cy1 == rbase + 1 ? ay1 : 0.f);
    unsigned short* gw = geow + i * 4;
    gw[0] = f2bf(gy0);
    gw[1] = f2bf(gy1);
    gw[2] = f2bf(gx0);
    gw[3] = f2bf(gx1);
    geoi[i] = (unsigned short)((rbase << 7) + cbase);
  }
  __syncthreads();   // the only block-wide barrier (protects geow/geoi)

  f32x4 acc[4][2];
#pragma unroll
  for (int mt = 0; mt < 4; ++mt)
#pragma unroll
    for (int nt = 0; nt < 2; ++nt) acc[mt][nt] = (f32x4){0.f, 0.f, 0.f, 0.f};

  const unsigned short* xtb = xt + ((size_t)(b << 14)) * 64;

#pragma unroll 2
  for (int it = 0; it < 20; ++it) {
    int chunk = it / 5, tp = it - chunk * 5;
    int ch0 = (chunk << 4) + (halfb << 3);
    // geometry for both taps of px pb
    float gy0[2], gy1[2], gx0[2], gx1[2];
    const unsigned short* cp[2];
#pragma unroll
    for (int s = 0; s < 2; ++s) {
      int tap = tp * 2 + s;
      if (tap < 9) {
        int gidx = (tap << 7) + pb;
        u16x4 wq = *(const u16x4*)(geow + gidx * 4);
        unsigned ib = geoi[gidx];
        gy0[s] = bf2f(wq[0]);
        gy1[s] = bf2f(wq[1]);
        gx0[s] = bf2f(wq[2]);
        gx1[s] = bf2f(wq[3]);
        cp[s] = xtb + ((size_t)ib) * 64 + ch0;
      } else {
        cp[s] = xtb + ch0;  // dead
        gy0[s] = gy1[s] = gx0[s] = gx1[s] = 0.f;
      }
    }
    // batched corner loads: 2 taps x 4 corners x (8ch dwordx4)
    s16x8 c00[2], c01[2], c10[2], c11[2];
#pragma unroll
    for (int s = 0; s < 2; ++s) {
      int tap = tp * 2 + s;
      if (tap < 9) {
        c00[s] = *(const s16x8*)(cp[s]);
        c01[s] = *(const s16x8*)(cp[s] + 64);
        c10[s] = *(const s16x8*)(cp[s] + 8192);
        c11[s] = *(const s16x8*)(cp[s] + 8192 + 64);
      }
    }
    s16x8 pk[2];
#pragma unroll
    for (int s = 0; s < 2; ++s) {
      int tap = tp * 2 + s;
      if (tap < 9) {
#pragma unroll
        for (int j = 0; j < 8; ++j) {
          float v = gy0[s] * (gx0[s] * bf2f((unsigned short)c00[s][j]) +
                              gx1[s] * bf2f((unsigned short)c01[s][j])) +
                    gy1[s] * (gx0[s] * bf2f((unsigned short)c10[s][j]) +
                              gx1[s] * bf2f((unsigned short)c11[s][j]));
          pk[s][j] = (short)f2bf(v);
        }
      } else {
#pragma unroll
        for (int j = 0; j < 8; ++j) pk[s][j] = 0;
      }
    }
    // wave-private staging: same addresses/values as R10, but writer == reader wave
    short* vd = vlds + (it & 1) * 5120 + pb * 40 + (halfb << 3);
    *(s16x8*)(vd) = pk[0];
    *(s16x8*)(vd + 16) = pk[1];
    // no __syncthreads: same-wave ds_write -> ds_read ordered by lgkmcnt
    const short* vb = vlds + (it & 1) * 5120;
    s16x8 B0 = *(const s16x8*)(vb + ((wv << 5) + l4) * 40 + (quad << 3));
    s16x8 B1 = *(const s16x8*)(vb + ((wv << 5) + 16 + l4) * 40 + (quad << 3));
#pragma unroll
    for (int mt = 0; mt < 4; ++mt) {
      s16x8 A = *(const s16x8*)(wbtB + (size_t)((it << 6) + (mt << 4) + l4) * 32 + (quad << 3));
      acc[mt][0] = __builtin_amdgcn_mfma_f32_16x16x32_bf16(A, B0, acc[mt][0], 0, 0, 0);
      acc[mt][1] = __builtin_amdgcn_mfma_f32_16x16x32_bf16(A, B1, acc[mt][1], 0, 0, 0);
    }
  }

#pragma unroll
  for (int mt = 0; mt < 4; ++mt)
#pragma unroll
    for (int r = 0; r < 4; ++r) {
      int oc = (mt << 4) + (quad << 2) + r;
      float bv = bias[oc];
      float* yp = y + (((size_t)(b << 6) + oc) << 14) + hw;
      yp[(wv << 5) + l4] = acc[mt][0][r] + bv;
      yp[(wv << 5) + 16 + l4] = acc[mt][1][r] + bv;
    }
}

// ---------------- kernel C: per-channel sum/sumsq (sliced, atomics into stat) ----------------
__global__ __launch_bounds__(256) void stats2_kernel(
    const float* __restrict__ y, float* __restrict__ stat) {
  int bxx = blockIdx.x;            // 1024 = 64 ch x 16 slices
  int c = bxx & 63, sl = bxx >> 6;
  int bb = sl >> 1;
  const float4* yp = (const float4*)(y + (((size_t)bb * 64 + c) << 14) + ((sl & 1) << 13));
  float s = 0.f, ss = 0.f;
  for (int i = threadIdx.x; i < 2048; i += 256) {
    float4 v = yp[i];
    s += v.x + v.y + v.z + v.w;
    ss += v.x * v.x + v.y * v.y + v.z * v.z + v.w * v.w;
  }
#pragma unroll
  for (int o = 32; o > 0; o >>= 1) {
    s += __shfl_xor(s, o);
    ss += __shfl_xor(ss, o);
  }
  __shared__ float shs[4], shss[4];
  int lane = threadIdx.x & 63, wv = threadIdx.x >> 6;
  if (lane == 0) { shs[wv] = s; shss[wv] = ss; }
  __syncthreads();
  if (threadIdx.x == 0) {
    float S = shs[0] + shs[1] + shs[2] + shs[3];
    float SS = shss[0] + shss[1] + shss[2] + shss[3];
    atomicAdd(stat + c, S);
    atomicAdd(stat + 64 + c, SS);
  }
}

// ---------------- kernel D: batchnorm scale/shift + relu, in place ----------------
__global__ __launch_bounds__(256) void bnrelu_kernel(
    float* __restrict__ y, const float* __restrict__ stat,
    const float* __restrict__ gamma, const float* __restrict__ beta) {
  float4* y4 = (float4*)y;
  for (int i = blockIdx.x * 256 + threadIdx.x; i < 2097152; i += gridDim.x * 256) {
    int c = (i >> 12) & 63;
    float mean = stat[c] * (1.f / (float)NPIX);
    float var = stat[64 + c] * (1.f / (float)NPIX) - mean * mean;
    float r = rsqrtf(var + EPSv);
    float g = gamma[c] * r;
    float bt = beta[c] - mean * g;
    float4 v = y4[i];
    v.x = fmaxf(v.x * g + bt, 0.f);
    v.y = fmaxf(v.y * g + bt, 0.f);
    v.z = fmaxf(v.z * g + bt, 0.f);
    v.w = fmaxf(v.w * g + bt, 0.f);
    y4[i] = v;
  }
}

extern "C" void kernel_launch(void* const* d_in, const int* in_sizes, int n_in,
                              void* d_out, int out_size, void* d_ws, size_t ws_size,
                              hipStream_t stream) {
  const float* x     = (const float*)d_in[0];
  const float* off_w = (const float*)d_in[1];
  const float* off_b = (const float*)d_in[2];
  const float* mod_w = (const float*)d_in[3];
  const float* mod_b = (const float*)d_in[4];
  const float* w     = (const float*)d_in[5];
  const float* b     = (const float*)d_in[6];
  const float* gamma = (const float*)d_in[7];
  const float* beta  = (const float*)d_in[8];
  float* out = (float*)d_out;
  float* ws  = (float*)d_ws;

  unsigned short* xt  = (unsigned short*)(ws + XT_OFF);
  float* offo  = ws + OFF_OFF;
  float* masko = ws + MASK_OFF;
  unsigned short* wbtA = (unsigned short*)(ws + WBTA_OFF);
  unsigned short* wbtB = (unsigned short*)(ws + WBTB_OFF);
  float* stat  = ws + STAT_OFF;

  prep_kernel<<<240, 256, 0, stream>>>(off_w, mod_w, w, wbtA, wbtB, stat);
  xform_kernel<<<512, 256, 0, stream>>>(x, xt);
  convA_mfma_kernel<<<1024, 256, 0, stream>>>(xt, wbtA, off_b, mod_b, offo, masko);
  deform_mfma_kernel<<<1024, 256, 0, stream>>>(xt, offo, masko, wbtB, b, out);
  stats2_kernel<<<1024, 256, 0, stream>>>(out, stat);
  bnrelu_kernel<<<8192, 256, 0, stream>>>(out, stat, gamma, beta);
}